// Round 2
// baseline (1438.763 us; speedup 1.0000x reference)
//
#include <hip/hip_runtime.h>
#include <hip/hip_bf16.h>

// AttentionConv2d: B=8, C_IN=256, H=W=32 (HW=1024), DK=DV=256, NH=8, DKH=DVH=32,
// C_OUT=512, 3x3 conv pad=1.
// Inputs/outputs are fp32 storage (bf16-quantized values; threshold = 2% of max|ref|).
//
// Workspace layout (bf16 elements, 16 MB total):
//   qT   [8][8][1024][32]  @ 0         (scaled by 32^-0.5)
//   kW   [8][8][32][1024]  @ 2097152   (d-major so attention LDS reads are conflict-free)
//   vW   [8][8][32][1024]  @ 4194304
//   attL [8][1024][256]    @ 6291456   (attention result, channel = h*32+d)

typedef __hip_bfloat16 bf16;

__device__ __forceinline__ float bf2f(bf16 v) { return __bfloat162float(v); }
__device__ __forceinline__ float blo(unsigned int v) { return __uint_as_float(v << 16); }
__device__ __forceinline__ float bhi(unsigned int v) { return __uint_as_float(v & 0xffff0000u); }

// ---------------------------------------------------------------------------
// K1: qkv 1x1 conv (GEMM 768 x 1024 x 256 per batch)
// block: 256 thr computes 64c x 64l tile; grid (16 ltile, 12 ctile, 8 b)
// ---------------------------------------------------------------------------
__global__ __launch_bounds__(256) void qkv_kernel(
    const float* __restrict__ x, const float* __restrict__ w, const float* __restrict__ bias,
    bf16* __restrict__ qT, bf16* __restrict__ kW, bf16* __restrict__ vW)
{
  __shared__ __align__(16) float wS[64 * 33];   // [c][ci] padded
  __shared__ __align__(16) float xS[32 * 64];   // [ci][l]
  int tid = threadIdx.x;
  int l0 = blockIdx.x * 64;
  int c0 = blockIdx.y * 64;
  int b  = blockIdx.z;
  int tx = tid & 15, ty = tid >> 4;

  float acc[4][4];
#pragma unroll
  for (int i = 0; i < 4; ++i)
#pragma unroll
    for (int j = 0; j < 4; ++j) acc[i][j] = 0.f;

  for (int kk0 = 0; kk0 < 256; kk0 += 32) {
    __syncthreads();
#pragma unroll
    for (int rep = 0; rep < 2; ++rep) {
      int idx4 = rep * 256 + tid;                // 0..511
      int i = idx4 >> 3;                          // c 0..63
      int j4 = idx4 & 7;                          // ci group of 4
      float4 wv = *(const float4*)(w + (size_t)(c0 + i) * 256 + kk0 + j4 * 4);
      wS[i * 33 + j4 * 4 + 0] = wv.x;
      wS[i * 33 + j4 * 4 + 1] = wv.y;
      wS[i * 33 + j4 * 4 + 2] = wv.z;
      wS[i * 33 + j4 * 4 + 3] = wv.w;
    }
#pragma unroll
    for (int rep = 0; rep < 2; ++rep) {
      int idx4 = rep * 256 + tid;                // 0..511
      int j = idx4 >> 4;                          // ci 0..31
      int i4 = idx4 & 15;                         // l group of 4
      *(float4*)(xS + j * 64 + i4 * 4) =
          *(const float4*)(x + (size_t)(b * 256 + kk0 + j) * 1024 + l0 + i4 * 4);
    }
    __syncthreads();
#pragma unroll
    for (int k = 0; k < 32; ++k) {
      float4 bv = *(const float4*)(xS + k * 64 + tx * 4);
#pragma unroll
      for (int s = 0; s < 4; ++s) {
        float a = wS[(ty * 4 + s) * 33 + k];
        acc[s][0] += a * bv.x; acc[s][1] += a * bv.y;
        acc[s][2] += a * bv.z; acc[s][3] += a * bv.w;
      }
    }
  }

#pragma unroll
  for (int s = 0; s < 4; ++s) {
    int c = c0 + ty * 4 + s;
    float bv = bias[c];
#pragma unroll
    for (int e = 0; e < 4; ++e) {
      int l = l0 + tx * 4 + e;
      float v = acc[s][e] + bv;
      if (c < 256) {
        int h = c >> 5, d = c & 31;
        qT[((size_t)(b * 8 + h) * 1024 + l) * 32 + d] =
            __float2bfloat16(v * 0.17677669529663689f);  // 32^-0.5, applied pre-rel-logits
      } else if (c < 512) {
        int c2 = c - 256;
        kW[((size_t)(b * 8 + (c2 >> 5)) * 32 + (c2 & 31)) * 1024 + l] = __float2bfloat16(v);
      } else {
        int c2 = c - 512;
        vW[((size_t)(b * 8 + (c2 >> 5)) * 32 + (c2 & 31)) * 1024 + l] = __float2bfloat16(v);
      }
    }
  }
}

// ---------------------------------------------------------------------------
// K2: attention. 1 query per wave, 4 waves/block. K/V chunks of 128 keys staged
// in LDS as [d][128] (conflict-free stride-1 reads across lanes). All 1024
// logits kept in 16 regs/lane. rel logits: per-query RW[32]/RH[32] tables.
// grid 16384 = B*NH*256 query-groups.
// ---------------------------------------------------------------------------
__global__ __launch_bounds__(256) void attn_kernel(
    const bf16* __restrict__ qT, const bf16* __restrict__ kW, const bf16* __restrict__ vW,
    const float* __restrict__ krw, const float* __restrict__ krh,
    bf16* __restrict__ attL)
{
  // [0..4096) staging (K in pass1, V in pass3); [0..8448) reduce (after pass3,
  // barrier-protected alias); [8448..8704) rw/rh tables (4 waves x 64).
  __shared__ __align__(16) float smem[8704];
  float* stg  = smem;
  float* red  = smem;
  float* rwrh = smem + 8448;

  int tid  = threadIdx.x;
  int lane = tid & 63, wave = tid >> 6;
  int bid = blockIdx.x;
  int qb = bid & 255;
  int h  = (bid >> 8) & 7;
  int b  = bid >> 11;
  int head = b * 8 + h;
  int l  = qb * 4 + wave;           // this wave's query
  int qx = l >> 5, qi = l & 31;     // query row / col

  float qreg[32];
  const bf16* qp = qT + ((size_t)head * 1024 + l) * 32;
#pragma unroll
  for (int d = 0; d < 32; ++d) qreg[d] = bf2f(qp[d]);

  {
    // lanes 0..31: RW[j] = q . krw[j-qi+31]; lanes 32..63: RH[x2] = q . krh[x2-qx+31]
    int col = lane & 31;
    const float* tbl = (lane >= 32) ? krh : krw;
    int row = (lane >= 32) ? (col - qx + 31) : (col - qi + 31);  // always in [0,62]
    float dot = 0.f;
#pragma unroll
    for (int d = 0; d < 32; ++d) dot += qreg[d] * tbl[row * 32 + d];
    rwrh[wave * 64 + lane] = dot;
  }
  __syncthreads();
  float rwv = rwrh[wave * 64 + (lane & 31)];   // RW for this lane's key-col (m&31 == lane&31)

  float Lv[16];
  float lmax = -1e30f;
  const bf16* kbase = kW + (size_t)head * 32768;
#pragma unroll
  for (int c = 0; c < 8; ++c) {
    __syncthreads();
#pragma unroll
    for (int rep = 0; rep < 2; ++rep) {
      int idx8 = rep * 256 + tid;                // 0..511, 8 bf16 each
      int d = idx8 >> 4, g = idx8 & 15;
      uint4 u = *(const uint4*)(kbase + d * 1024 + c * 128 + g * 8);
      float* dst = stg + d * 128 + g * 8;
      ((float4*)dst)[0] = make_float4(blo(u.x), bhi(u.x), blo(u.y), bhi(u.y));
      ((float4*)dst)[1] = make_float4(blo(u.z), bhi(u.z), blo(u.w), bhi(u.w));
    }
    __syncthreads();
#pragma unroll
    for (int kk = 0; kk < 2; ++kk) {
      int mloc = kk * 64 + lane;
      float dot = 0.f;
#pragma unroll
      for (int d = 0; d < 32; ++d) dot += qreg[d] * stg[d * 128 + mloc];
      float logit = dot + rwv + rwrh[wave * 64 + 32 + (c * 4 + kk * 2 + (lane >> 5))];
      Lv[c * 2 + kk] = logit;
      lmax = fmaxf(lmax, logit);
    }
  }
#pragma unroll
  for (int off = 32; off > 0; off >>= 1) lmax = fmaxf(lmax, __shfl_xor(lmax, off, 64));
  float lsum = 0.f;
#pragma unroll
  for (int i = 0; i < 16; ++i) { Lv[i] = __expf(Lv[i] - lmax); lsum += Lv[i]; }
#pragma unroll
  for (int off = 32; off > 0; off >>= 1) lsum += __shfl_xor(lsum, off, 64);
  float inv = 1.0f / lsum;

  float acc[32];
#pragma unroll
  for (int d = 0; d < 32; ++d) acc[d] = 0.f;
  const bf16* vbase = vW + (size_t)head * 32768;
#pragma unroll
  for (int c = 0; c < 8; ++c) {
    __syncthreads();
#pragma unroll
    for (int rep = 0; rep < 2; ++rep) {
      int idx8 = rep * 256 + tid;
      int d = idx8 >> 4, g = idx8 & 15;
      uint4 u = *(const uint4*)(vbase + d * 1024 + c * 128 + g * 8);
      float* dst = stg + d * 128 + g * 8;
      ((float4*)dst)[0] = make_float4(blo(u.x), bhi(u.x), blo(u.y), bhi(u.y));
      ((float4*)dst)[1] = make_float4(blo(u.z), bhi(u.z), blo(u.w), bhi(u.w));
    }
    __syncthreads();
#pragma unroll
    for (int kk = 0; kk < 2; ++kk) {
      int mloc = kk * 64 + lane;
      float pv = Lv[c * 2 + kk];
#pragma unroll
      for (int d = 0; d < 32; ++d) acc[d] += pv * stg[d * 128 + mloc];
    }
  }
  __syncthreads();   // all waves done with stg; safe to alias as reduce scratch
#pragma unroll
  for (int d = 0; d < 32; ++d) red[wave * 2112 + lane * 33 + d] = acc[d];
  __syncthreads();
  if (lane < 32) {
    float s = 0.f;
#pragma unroll 8
    for (int s2 = 0; s2 < 64; ++s2) s += red[wave * 2112 + s2 * 33 + lane];
    attL[((size_t)b * 1024 + l) * 256 + h * 32 + lane] = __float2bfloat16(s * inv);
  }
}

// ---------------------------------------------------------------------------
// K3: 3x3 conv, pad 1, 256->256 (output channels 0..255).
// block: 32co x (2 rows x 4 col-groups of 8); ci chunks of 16 staged in LDS.
// grid 1024 = b(8) x cotile(8) x rowtile(16).
// ---------------------------------------------------------------------------
__global__ __launch_bounds__(256) void conv3_kernel(
    const float* __restrict__ x, const float* __restrict__ w, const float* __restrict__ bias,
    float* __restrict__ out)
{
  __shared__ __align__(16) float xS[2304];   // [16ci][4 rows][36 cols]
  __shared__ __align__(16) float wS[4752];   // [144 = ci*9+k][33 co-padded]
  int tid = threadIdx.x;
  int bid = blockIdx.x;
  int rowtile = bid & 15;
  int cotile  = (bid >> 4) & 7;
  int b       = bid >> 7;
  int co_l = tid & 31;
  int slot = tid >> 5;
  int r  = slot >> 2;     // 0..1
  int cg = slot & 3;      // col-group of 8
  int r0 = rowtile * 2;

  float acc[8];
#pragma unroll
  for (int e = 0; e < 8; ++e) acc[e] = 0.f;

  for (int cic = 0; cic < 16; ++cic) {
    __syncthreads();
#pragma unroll
    for (int rep = 0; rep < 9; ++rep) {
      int idx = rep * 256 + tid;               // 2304 = 9*256 exact
      int ci_l = idx / 144;
      int rem  = idx - ci_l * 144;
      int yy = rem / 36;
      int xx = rem - yy * 36;
      int gy = r0 + yy - 1;
      int gx = xx - 1;
      float v = 0.f;
      if (gy >= 0 && gy < 32 && gx >= 0 && gx < 32)
        v = x[((size_t)(b * 256 + cic * 16 + ci_l) * 32 + gy) * 32 + gx];
      xS[idx] = v;
    }
#pragma unroll
    for (int rep = 0; rep < 18; ++rep) {
      int idx = rep * 256 + tid;               // 4608 = 18*256 exact
      int co   = idx / 144;
      int kidx = idx - co * 144;               // ci_l*9 + k9
      wS[kidx * 33 + co] = w[((size_t)(cotile * 32 + co) * 256 + cic * 16) * 9 + kidx];
    }
    __syncthreads();
#pragma unroll 2
    for (int ci = 0; ci < 16; ++ci) {
#pragma unroll
      for (int dy = 0; dy < 3; ++dy) {
        const float* rowp = xS + ci * 144 + (r + dy) * 36 + cg * 8;
        float4 a0 = ((const float4*)rowp)[0];
        float4 a1 = ((const float4*)rowp)[1];
        float4 a2 = ((const float4*)rowp)[2];
        float xr[12] = {a0.x, a0.y, a0.z, a0.w, a1.x, a1.y, a1.z, a1.w,
                        a2.x, a2.y, a2.z, a2.w};
#pragma unroll
        for (int dx = 0; dx < 3; ++dx) {
          float wv = wS[(ci * 9 + dy * 3 + dx) * 33 + co_l];
#pragma unroll
          for (int e = 0; e < 8; ++e) acc[e] += wv * xr[e + dx];
        }
      }
    }
  }

  int co = cotile * 32 + co_l;
  float bv = bias[co];
  int orow = r0 + r;
  size_t obase = ((size_t)(b * 512 + co)) * 1024 + orow * 32 + cg * 8;
#pragma unroll
  for (int e = 0; e < 8; ++e) out[obase + e] = acc[e] + bv;
}

// ---------------------------------------------------------------------------
// K4: 1x1 conv on attention result -> output channels 256..511.
// block: 256 thr = all co, 4 spatial positions; grid 2048 = b(8) x lgroup(256).
// ---------------------------------------------------------------------------
__global__ __launch_bounds__(256) void attnout_kernel(
    const bf16* __restrict__ attL, const float* __restrict__ w, const float* __restrict__ bias,
    float* __restrict__ out)
{
  __shared__ __align__(16) float aL[1024];   // [4 l][256 c]
  int tid = threadIdx.x;
  int lg = blockIdx.x & 255;
  int b  = blockIdx.x >> 8;
  int l0 = lg * 4;
#pragma unroll
  for (int rep = 0; rep < 4; ++rep) {
    int idx = rep * 256 + tid;
    aL[idx] = bf2f(attL[((size_t)b * 1024 + l0) * 256 + idx]);
  }
  __syncthreads();

  float acc[4] = {0.f, 0.f, 0.f, 0.f};
  const float* wrow = w + (size_t)tid * 256;
  for (int c8 = 0; c8 < 32; ++c8) {
    float4 wa = ((const float4*)wrow)[c8 * 2];
    float4 wb = ((const float4*)wrow)[c8 * 2 + 1];
    float wv[8] = {wa.x, wa.y, wa.z, wa.w, wb.x, wb.y, wb.z, wb.w};
#pragma unroll
    for (int e = 0; e < 8; ++e) {
#pragma unroll
      for (int j = 0; j < 4; ++j) acc[j] += wv[e] * aL[j * 256 + c8 * 8 + e];
    }
  }
  float bv = bias[tid];
  size_t obase = ((size_t)(b * 512 + 256 + tid)) * 1024 + l0;
#pragma unroll
  for (int j = 0; j < 4; ++j) out[obase + j] = acc[j] + bv;
}

// ---------------------------------------------------------------------------
extern "C" void kernel_launch(void* const* d_in, const int* in_sizes, int n_in,
                              void* d_out, int out_size, void* d_ws, size_t ws_size,
                              hipStream_t stream) {
  const float* x      = (const float*)d_in[0];
  const float* w_qkv  = (const float*)d_in[1];
  const float* b_qkv  = (const float*)d_in[2];
  const float* w_attn = (const float*)d_in[3];
  const float* b_attn = (const float*)d_in[4];
  const float* w_out  = (const float*)d_in[5];
  const float* b_out  = (const float*)d_in[6];
  const float* krw    = (const float*)d_in[7];
  const float* krh    = (const float*)d_in[8];
  float* out = (float*)d_out;

  bf16* qT   = (bf16*)d_ws;            // 2097152 bf16
  bf16* kW   = qT + 2097152;           // 2097152
  bf16* vW   = kW + 2097152;           // 2097152
  bf16* attL = vW + 2097152;           // 2097152  (total 16 MB)

  qkv_kernel<<<dim3(16, 12, 8), 256, 0, stream>>>(x, w_qkv, b_qkv, qT, kW, vW);
  conv3_kernel<<<dim3(1024), 256, 0, stream>>>(x, w_out, b_out, out);
  attn_kernel<<<dim3(16384), 256, 0, stream>>>(qT, kW, vW, krw, krh, attL);
  attnout_kernel<<<dim3(2048), 256, 0, stream>>>(attL, w_attn, b_attn, out);
}

// Round 3
// 589.786 us; speedup vs baseline: 2.4395x; 2.4395x over previous
//
#include <hip/hip_runtime.h>
#include <hip/hip_bf16.h>

// AttentionConv2d: B=8, C_IN=256, H=W=32 (HW=1024), DK=DV=256, NH=8, DKH=DVH=32,
// C_OUT=512, 3x3 conv pad=1. fp32 storage in/out; bf16 intermediates.
//
// Workspace (bf16 elements, 16 MB):
//   qT   [64 head][1024 l][32 d]   @ 0          (scaled by 32^-0.5)
//   kR   [64 head][1024 key][32 d] @ 2097152    (key-major for MFMA B-frag staging)
//   vW   [64 head][32 d][1024 key] @ 4194304
//   attL [8 b][1024 l][256 ch]     @ 6291456    (ch = h*32+d)

typedef __hip_bfloat16 bf16;
typedef __attribute__((ext_vector_type(8))) short bf16x8;
typedef __attribute__((ext_vector_type(4))) float f32x4;

__device__ __forceinline__ float bf2f(bf16 v) { return __bfloat162float(v); }
__device__ __forceinline__ float blo(unsigned int v) { return __uint_as_float(v << 16); }
__device__ __forceinline__ float bhi(unsigned int v) { return __uint_as_float(v & 0xffff0000u); }
__device__ __forceinline__ unsigned short f2bfbits(float f) {
  union { bf16 h; unsigned short u; } cv; cv.h = __float2bfloat16(f); return cv.u;
}

// ---------------------------------------------------------------------------
// K1: qkv 1x1 conv (GEMM 768 x 1024 x 256 per batch)
// ---------------------------------------------------------------------------
__global__ __launch_bounds__(256) void qkv_kernel(
    const float* __restrict__ x, const float* __restrict__ w, const float* __restrict__ bias,
    bf16* __restrict__ qT, bf16* __restrict__ kR, bf16* __restrict__ vW)
{
  __shared__ __align__(16) float wS[64 * 33];   // [c][ci] padded
  __shared__ __align__(16) float xS[32 * 64];   // [ci][l]
  int tid = threadIdx.x;
  int l0 = blockIdx.x * 64;
  int c0 = blockIdx.y * 64;
  int b  = blockIdx.z;
  int tx = tid & 15, ty = tid >> 4;

  float acc[4][4];
#pragma unroll
  for (int i = 0; i < 4; ++i)
#pragma unroll
    for (int j = 0; j < 4; ++j) acc[i][j] = 0.f;

  for (int kk0 = 0; kk0 < 256; kk0 += 32) {
    __syncthreads();
#pragma unroll
    for (int rep = 0; rep < 2; ++rep) {
      int idx4 = rep * 256 + tid;
      int i = idx4 >> 3;
      int j4 = idx4 & 7;
      float4 wv = *(const float4*)(w + (size_t)(c0 + i) * 256 + kk0 + j4 * 4);
      wS[i * 33 + j4 * 4 + 0] = wv.x;
      wS[i * 33 + j4 * 4 + 1] = wv.y;
      wS[i * 33 + j4 * 4 + 2] = wv.z;
      wS[i * 33 + j4 * 4 + 3] = wv.w;
    }
#pragma unroll
    for (int rep = 0; rep < 2; ++rep) {
      int idx4 = rep * 256 + tid;
      int j = idx4 >> 4;
      int i4 = idx4 & 15;
      *(float4*)(xS + j * 64 + i4 * 4) =
          *(const float4*)(x + (size_t)(b * 256 + kk0 + j) * 1024 + l0 + i4 * 4);
    }
    __syncthreads();
#pragma unroll
    for (int k = 0; k < 32; ++k) {
      float4 bv = *(const float4*)(xS + k * 64 + tx * 4);
#pragma unroll
      for (int s = 0; s < 4; ++s) {
        float a = wS[(ty * 4 + s) * 33 + k];
        acc[s][0] += a * bv.x; acc[s][1] += a * bv.y;
        acc[s][2] += a * bv.z; acc[s][3] += a * bv.w;
      }
    }
  }

#pragma unroll
  for (int s = 0; s < 4; ++s) {
    int c = c0 + ty * 4 + s;
    float bv = bias[c];
#pragma unroll
    for (int e = 0; e < 4; ++e) {
      int l = l0 + tx * 4 + e;
      float v = acc[s][e] + bv;
      if (c < 256) {
        int h = c >> 5, d = c & 31;
        qT[((size_t)(b * 8 + h) * 1024 + l) * 32 + d] =
            __float2bfloat16(v * 0.17677669529663689f);  // 32^-0.5, pre-rel-logits
      } else if (c < 512) {
        int c2 = c - 256;
        kR[((size_t)(b * 8 + (c2 >> 5)) * 1024 + l) * 32 + (c2 & 31)] = __float2bfloat16(v);
      } else {
        int c2 = c - 512;
        vW[((size_t)(b * 8 + (c2 >> 5)) * 32 + (c2 & 31)) * 1024 + l] = __float2bfloat16(v);
      }
    }
  }
}

// ---------------------------------------------------------------------------
// K2: MFMA attention with augmented-K rel logits.
// Block = (head, qtile of 64 rows); 4 waves x 16 q-rows. grid 1024.
// Aaug row l = [q(32) | RW[l](32) | RH[l](32)]; Baug key m = [k(32) | 1hot(mx) | 1hot(my)]
// logit = Aaug . Baug exactly. No-max softmax (logits bounded ~±8), single pass.
// ---------------------------------------------------------------------------
__global__ __launch_bounds__(256) void attn_mfma_kernel(
    const bf16* __restrict__ qT, const bf16* __restrict__ kR, const bf16* __restrict__ vW,
    const float* __restrict__ krw, const float* __restrict__ krh,
    bf16* __restrict__ attL)
{
  // Regions: A [0,13312) Kaug[64][104]; B [13312,17920) VT[32][72];
  //          C [17920,31232) Atile[64][104] (prologue) / P[4][16][72] (K-loop).
  // Prologue phase0/1 also aliases A+B as krwS[63][33] + krhS[63][33] (f32).
  __shared__ __align__(16) char smem[31232];
  short* kaugS  = (short*)smem;
  short* vtS    = (short*)(smem + 13312);
  short* atileS = (short*)(smem + 17920);
  float* krwS   = (float*)smem;
  float* krhS   = krwS + 63 * 33;

  int tid = threadIdx.x;
  int lane = tid & 63, wave = tid >> 6;
  int m16 = lane & 15, quad = lane >> 4;
  int qt = blockIdx.x & 15, head = blockIdx.x >> 4;
  int row0 = qt * 64;
  int b = head >> 3, h = head & 7;

  // ---- phase 0: stage krw/krh (padded x33) and q rows into Atile ----
  for (int i = tid; i < 504; i += 256) {   // 63*32/4 = 504 float4 per table
    int row = i >> 3, d0 = (i & 7) * 4;
    float4 a = *(const float4*)(krw + row * 32 + d0);
    krwS[row * 33 + d0 + 0] = a.x; krwS[row * 33 + d0 + 1] = a.y;
    krwS[row * 33 + d0 + 2] = a.z; krwS[row * 33 + d0 + 3] = a.w;
    float4 c = *(const float4*)(krh + row * 32 + d0);
    krhS[row * 33 + d0 + 0] = c.x; krhS[row * 33 + d0 + 1] = c.y;
    krhS[row * 33 + d0 + 2] = c.z; krhS[row * 33 + d0 + 3] = c.w;
  }
  {
    int r = tid >> 2, seg = tid & 3;
    uint4 u = *(const uint4*)(qT + ((size_t)head * 1024 + row0 + r) * 32 + seg * 8);
    *(uint4*)(atileS + r * 104 + seg * 8) = u;
  }
  __syncthreads();

  // ---- phase 1: RW/RH tables -> Atile[.][32..96) ----
  {
    int r = tid >> 2, jseg = tid & 3;
    int qi = r & 31;
    int qx = qt * 2 + (r >> 5);
    float q32[32];
#pragma unroll
    for (int s4 = 0; s4 < 4; ++s4) {
      uint4 u = ((const uint4*)(atileS + r * 104))[s4];
      q32[s4 * 8 + 0] = blo(u.x); q32[s4 * 8 + 1] = bhi(u.x);
      q32[s4 * 8 + 2] = blo(u.y); q32[s4 * 8 + 3] = bhi(u.y);
      q32[s4 * 8 + 4] = blo(u.z); q32[s4 * 8 + 5] = bhi(u.z);
      q32[s4 * 8 + 6] = blo(u.w); q32[s4 * 8 + 7] = bhi(u.w);
    }
    unsigned int pw[4], ph[4];
#pragma unroll
    for (int jp = 0; jp < 4; ++jp) {
      float sv[4] = {0.f, 0.f, 0.f, 0.f};   // rw0, rw1, rh0, rh1
#pragma unroll 2
      for (int half = 0; half < 2; ++half) {
        int j = jseg * 8 + jp * 2 + half;
        const float* kw = krwS + (j - qi + 31) * 33;
        const float* kh = krhS + (j - qx + 31) * 33;
        float s1 = 0.f, s2 = 0.f;
#pragma unroll
        for (int d = 0; d < 32; ++d) { s1 += q32[d] * kw[d]; s2 += q32[d] * kh[d]; }
        sv[half] = s1; sv[2 + half] = s2;
      }
      pw[jp] = (unsigned int)f2bfbits(sv[0]) | ((unsigned int)f2bfbits(sv[1]) << 16);
      ph[jp] = (unsigned int)f2bfbits(sv[2]) | ((unsigned int)f2bfbits(sv[3]) << 16);
    }
#pragma unroll
    for (int jp = 0; jp < 4; ++jp) {
      ((unsigned int*)(atileS + r * 104 + 32 + jseg * 8))[jp] = pw[jp];
      ((unsigned int*)(atileS + r * 104 + 64 + jseg * 8))[jp] = ph[jp];
    }
  }
  __syncthreads();

  // ---- phase 2: load persistent A-frags (q | RW | RH) ----
  bf16x8 afrag[3];
  {
    int arow = wave * 16 + m16;
#pragma unroll
    for (int ks = 0; ks < 3; ++ks)
      afrag[ks] = *(const bf16x8*)(atileS + arow * 104 + ks * 32 + quad * 8);
  }

  // ---- K-loop over 16 chunks of 64 keys ----
  f32x4 oacc[2];
  oacc[0] = (f32x4){0.f, 0.f, 0.f, 0.f};
  oacc[1] = (f32x4){0.f, 0.f, 0.f, 0.f};
  float rsp[4] = {0.f, 0.f, 0.f, 0.f};
  short* pS = (short*)(smem + 17920) + wave * 1152;   // [16 q][72 key-padded]

  for (int c = 0; c < 16; ++c) {
    __syncthreads();
    {
      // Kaug k-part + one-hot
      int key = tid >> 2, seg = tid & 3;
      uint4 u = *(const uint4*)(kR + ((size_t)head * 1024 + c * 64 + key) * 32 + seg * 8);
      *(uint4*)(kaugS + key * 104 + seg * 8) = u;
      int gkey = c * 64 + key;
      int mx = gkey & 31, my = gkey >> 5;
      union { short s[16]; uint4 u4[2]; } oh;
#pragma unroll
      for (int e = 0; e < 16; ++e) {
        int j = seg * 16 + e;
        short v;
        if (j < 32) v = (j == mx) ? (short)0x3F80 : (short)0;
        else        v = ((j - 32) == my) ? (short)0x3F80 : (short)0;
        oh.s[e] = v;
      }
      ((uint4*)(kaugS + key * 104 + 32 + seg * 16))[0] = oh.u4[0];
      *((uint4*)(kaugS + key * 104 + 32 + seg * 16) + 1) = oh.u4[1];
    }
    {
      // VT chunk [32 d][64 keys] padded to 72
      int d = tid >> 3, kseg = tid & 7;
      uint4 u = *(const uint4*)(vW + (size_t)head * 32768 + d * 1024 + c * 64 + kseg * 8);
      *(uint4*)(vtS + d * 72 + kseg * 8) = u;
    }
    __syncthreads();

    // QK^T (augmented K-dim 96): 4 n-tiles x 3 k-steps
    f32x4 sacc[4];
#pragma unroll
    for (int t = 0; t < 4; ++t) sacc[t] = (f32x4){0.f, 0.f, 0.f, 0.f};
#pragma unroll
    for (int t = 0; t < 4; ++t) {
#pragma unroll
      for (int ks = 0; ks < 3; ++ks) {
        bf16x8 bfK = *(const bf16x8*)(kaugS + (t * 16 + m16) * 104 + ks * 32 + quad * 8);
        sacc[t] = __builtin_amdgcn_mfma_f32_16x16x32_bf16(afrag[ks], bfK, sacc[t], 0, 0, 0);
      }
    }
    // exp (no max-sub: logits bounded), row-sum partials, P -> LDS (C/D->A transform)
#pragma unroll
    for (int t = 0; t < 4; ++t) {
#pragma unroll
      for (int i = 0; i < 4; ++i) {
        float e = __expf(sacc[t][i]);
        rsp[i] += e;
        pS[(quad * 4 + i) * 72 + t * 16 + m16] = (short)f2bfbits(e);
      }
    }
    // PV: 2 k-steps (32 keys) x 2 d-tiles
#pragma unroll
    for (int ks2 = 0; ks2 < 2; ++ks2) {
      bf16x8 pf = *(const bf16x8*)(pS + m16 * 72 + ks2 * 32 + quad * 8);
#pragma unroll
      for (int dt = 0; dt < 2; ++dt) {
        bf16x8 vf = *(const bf16x8*)(vtS + (dt * 16 + m16) * 72 + ks2 * 32 + quad * 8);
        oacc[dt] = __builtin_amdgcn_mfma_f32_16x16x32_bf16(pf, vf, oacc[dt], 0, 0, 0);
      }
    }
  }

  // ---- epilogue: reduce row-sums within quad, normalize, store ----
#pragma unroll
  for (int off = 1; off < 16; off <<= 1)
#pragma unroll
    for (int i = 0; i < 4; ++i) rsp[i] += __shfl_xor(rsp[i], off, 64);
#pragma unroll
  for (int i = 0; i < 4; ++i) {
    float invs = 1.0f / rsp[i];
    int grow = row0 + wave * 16 + quad * 4 + i;
#pragma unroll
    for (int dt = 0; dt < 2; ++dt) {
      attL[((size_t)b * 1024 + grow) * 256 + h * 32 + dt * 16 + m16] =
          __float2bfloat16(oacc[dt][i] * invs);
    }
  }
}

// ---------------------------------------------------------------------------
// K3: 3x3 conv, pad 1, 256->256 (output channels 0..255).
// ---------------------------------------------------------------------------
__global__ __launch_bounds__(256) void conv3_kernel(
    const float* __restrict__ x, const float* __restrict__ w, const float* __restrict__ bias,
    float* __restrict__ out)
{
  __shared__ __align__(16) float xS[2304];   // [16ci][4 rows][36 cols]
  __shared__ __align__(16) float wS[4752];   // [144][33 co-padded]
  int tid = threadIdx.x;
  int bid = blockIdx.x;
  int rowtile = bid & 15;
  int cotile  = (bid >> 4) & 7;
  int b       = bid >> 7;
  int co_l = tid & 31;
  int slot = tid >> 5;
  int r  = slot >> 2;
  int cg = slot & 3;
  int r0 = rowtile * 2;

  float acc[8];
#pragma unroll
  for (int e = 0; e < 8; ++e) acc[e] = 0.f;

  for (int cic = 0; cic < 16; ++cic) {
    __syncthreads();
#pragma unroll
    for (int rep = 0; rep < 9; ++rep) {
      int idx = rep * 256 + tid;
      int ci_l = idx / 144;
      int rem  = idx - ci_l * 144;
      int yy = rem / 36;
      int xx = rem - yy * 36;
      int gy = r0 + yy - 1;
      int gx = xx - 1;
      float v = 0.f;
      if (gy >= 0 && gy < 32 && gx >= 0 && gx < 32)
        v = x[((size_t)(b * 256 + cic * 16 + ci_l) * 32 + gy) * 32 + gx];
      xS[idx] = v;
    }
#pragma unroll
    for (int rep = 0; rep < 18; ++rep) {
      int idx = rep * 256 + tid;
      int co   = idx / 144;
      int kidx = idx - co * 144;
      wS[kidx * 33 + co] = w[((size_t)(cotile * 32 + co) * 256 + cic * 16) * 9 + kidx];
    }
    __syncthreads();
#pragma unroll 2
    for (int ci = 0; ci < 16; ++ci) {
#pragma unroll
      for (int dy = 0; dy < 3; ++dy) {
        const float* rowp = xS + ci * 144 + (r + dy) * 36 + cg * 8;
        float4 a0 = ((const float4*)rowp)[0];
        float4 a1 = ((const float4*)rowp)[1];
        float4 a2 = ((const float4*)rowp)[2];
        float xr[12] = {a0.x, a0.y, a0.z, a0.w, a1.x, a1.y, a1.z, a1.w,
                        a2.x, a2.y, a2.z, a2.w};
#pragma unroll
        for (int dx = 0; dx < 3; ++dx) {
          float wv = wS[(ci * 9 + dy * 3 + dx) * 33 + co_l];
#pragma unroll
          for (int e = 0; e < 8; ++e) acc[e] += wv * xr[e + dx];
        }
      }
    }
  }

  int co = cotile * 32 + co_l;
  float bv = bias[co];
  int orow = r0 + r;
  size_t obase = ((size_t)(b * 512 + co)) * 1024 + orow * 32 + cg * 8;
#pragma unroll
  for (int e = 0; e < 8; ++e) out[obase + e] = acc[e] + bv;
}

// ---------------------------------------------------------------------------
// K4: 1x1 conv on attention result -> output channels 256..511.
// ---------------------------------------------------------------------------
__global__ __launch_bounds__(256) void attnout_kernel(
    const bf16* __restrict__ attL, const float* __restrict__ w, const float* __restrict__ bias,
    float* __restrict__ out)
{
  __shared__ __align__(16) float aL[1024];   // [4 l][256 c]
  int tid = threadIdx.x;
  int lg = blockIdx.x & 255;
  int b  = blockIdx.x >> 8;
  int l0 = lg * 4;
#pragma unroll
  for (int rep = 0; rep < 4; ++rep) {
    int idx = rep * 256 + tid;
    aL[idx] = bf2f(attL[((size_t)b * 1024 + l0) * 256 + idx]);
  }
  __syncthreads();

  float acc[4] = {0.f, 0.f, 0.f, 0.f};
  const float* wrow = w + (size_t)tid * 256;
  for (int c8 = 0; c8 < 32; ++c8) {
    float4 wa = ((const float4*)wrow)[c8 * 2];
    float4 wb = ((const float4*)wrow)[c8 * 2 + 1];
    float wv[8] = {wa.x, wa.y, wa.z, wa.w, wb.x, wb.y, wb.z, wb.w};
#pragma unroll
    for (int e = 0; e < 8; ++e) {
#pragma unroll
      for (int j = 0; j < 4; ++j) acc[j] += wv[e] * aL[j * 256 + c8 * 8 + e];
    }
  }
  float bv = bias[tid];
  size_t obase = ((size_t)(b * 512 + 256 + tid)) * 1024 + l0;
#pragma unroll
  for (int j = 0; j < 4; ++j) out[obase + j] = acc[j] + bv;
}

// ---------------------------------------------------------------------------
extern "C" void kernel_launch(void* const* d_in, const int* in_sizes, int n_in,
                              void* d_out, int out_size, void* d_ws, size_t ws_size,
                              hipStream_t stream) {
  const float* x      = (const float*)d_in[0];
  const float* w_qkv  = (const float*)d_in[1];
  const float* b_qkv  = (const float*)d_in[2];
  const float* w_attn = (const float*)d_in[3];
  const float* b_attn = (const float*)d_in[4];
  const float* w_out  = (const float*)d_in[5];
  const float* b_out  = (const float*)d_in[6];
  const float* krw    = (const float*)d_in[7];
  const float* krh    = (const float*)d_in[8];
  float* out = (float*)d_out;

  bf16* qT   = (bf16*)d_ws;            // 2097152 bf16
  bf16* kR   = qT + 2097152;
  bf16* vW   = kR + 2097152;
  bf16* attL = vW + 2097152;           // total 16 MB

  qkv_kernel<<<dim3(16, 12, 8), 256, 0, stream>>>(x, w_qkv, b_qkv, qT, kR, vW);
  conv3_kernel<<<dim3(1024), 256, 0, stream>>>(x, w_out, b_out, out);
  attn_mfma_kernel<<<dim3(1024), 256, 0, stream>>>(qT, kR, vW, krw, krh, attL);
  attnout_kernel<<<dim3(2048), 256, 0, stream>>>(attL, w_attn, b_attn, out);
}

// Round 4
// 238.391 us; speedup vs baseline: 6.0353x; 2.4740x over previous
//
#include <hip/hip_runtime.h>
#include <hip/hip_bf16.h>

// AttentionConv2d: B=8, C_IN=256, H=W=32 (HW=1024), DK=DV=256, NH=8, DKH=DVH=32,
// C_OUT=512, 3x3 conv pad=1. fp32 storage in/out; bf16 intermediates + MFMA.
//
// Workspace (bf16 elements, EXACTLY 16 MB = 8,388,608 bf16 — proven safe size):
//   xT    [8 b][1024 l][256 ci]  @ 0          (dead after qkv)  } aliased later by
//   attL  [8 b][1024 l][256 ch]  @ 0          (attn -> attnout) } each other
//   wo_bf chunk-blocked          @ 2,097,152  (589,824; dead after conv3)
//   qT    [64 head][1024][32]    @ 2,097,152  (written by qkv AFTER conv3 -> safe alias)
//   kR    [64 head][1024][32]    @ 4,194,304
//   vW    [64 head][32][1024]    @ 6,291,456  (ends exactly 8,388,608)
// Kernel order: prep -> conv3 -> qkv -> attn -> attnout (stream-serial).

typedef __hip_bfloat16 bf16;
typedef __attribute__((ext_vector_type(8))) short bf16x8;
typedef __attribute__((ext_vector_type(4))) float f32x4;

__device__ __forceinline__ float bf2f(bf16 v) { return __bfloat162float(v); }
__device__ __forceinline__ float blo(unsigned int v) { return __uint_as_float(v << 16); }
__device__ __forceinline__ float bhi(unsigned int v) { return __uint_as_float(v & 0xffff0000u); }
__device__ __forceinline__ unsigned short f2bfbits(float f) {
  union { bf16 h; unsigned short u; } cv; cv.h = __float2bfloat16(f); return cv.u;
}

// ---------------------------------------------------------------------------
// K0: prep — xT transpose to bf16 + w_out bf16 chunk-blocked.
// blocks 0..2047: xT; 2048..2083: w_out. grid 2084.
// w_out_bf layout: [(co>>6)*8 + (ci>>5)][co&63][kidx 9][ci&31]  (18432 bf16/chunkblk)
// ---------------------------------------------------------------------------
__global__ __launch_bounds__(256) void prep_kernel(
    const float* __restrict__ x, const float* __restrict__ wout,
    bf16* __restrict__ xT, bf16* __restrict__ wo_bf)
{
  int bid = blockIdx.x, tid = threadIdx.x;
  if (bid < 2048) {
    __shared__ float t[32 * 33];
    int b = bid >> 8, rem = bid & 255;
    int ci0 = (rem >> 5) * 32, l0 = (rem & 31) * 32;
    {
      int ciL = tid >> 3, lL4 = (tid & 7) * 4;
      float4 v = *(const float4*)(x + (size_t)(b * 256 + ci0 + ciL) * 1024 + l0 + lL4);
      t[ciL * 33 + lL4 + 0] = v.x; t[ciL * 33 + lL4 + 1] = v.y;
      t[ciL * 33 + lL4 + 2] = v.z; t[ciL * 33 + lL4 + 3] = v.w;
    }
    __syncthreads();
    {
      int lL = tid >> 3, cS = (tid & 7) * 4;
      unsigned int p0 = (unsigned int)f2bfbits(t[(cS + 0) * 33 + lL]) |
                        ((unsigned int)f2bfbits(t[(cS + 1) * 33 + lL]) << 16);
      unsigned int p1 = (unsigned int)f2bfbits(t[(cS + 2) * 33 + lL]) |
                        ((unsigned int)f2bfbits(t[(cS + 3) * 33 + lL]) << 16);
      uint2 u2; u2.x = p0; u2.y = p1;
      *(uint2*)(xT + ((size_t)(b * 1024) + l0 + lL) * 256 + ci0 + cS) = u2;
    }
  } else {
    int t0 = (bid - 2048) * 256 + tid;       // 0..9215
#pragma unroll
    for (int s = 0; s < 8; ++s) {
      int u = s * 9216 + t0;                 // dst uint4 index 0..73727
      int chunkblk = u / 2304;
      int within = u - chunkblk * 2304;
      int co63 = within / 36;
      int r = within - co63 * 36;            // kidx*4 + cig
      int kidx = r >> 2, cig = r & 3;
      int co = (chunkblk >> 3) * 64 + co63;
      int ci = (chunkblk & 7) * 32 + cig * 8;
      union { unsigned short h[8]; uint4 u4; } pk;
#pragma unroll
      for (int j = 0; j < 8; ++j)
        pk.h[j] = f2bfbits(wout[(size_t)(co * 256 + ci + j) * 9 + kidx]);
      *(uint4*)(wo_bf + (size_t)u * 8) = pk.u4;
    }
  }
}

// ---------------------------------------------------------------------------
// K1: 3x3 conv 256->256 via 9 shift-GEMMs, MFMA bf16.
// Block: 64 co x 128 spatial (4 rows). grid 256 = b(8) x cotile(4) x rowchunk(8).
// LDS: wS[64 co][296] (288 = 9 kidx * 32 ci), xS[6 rows][34 cols][40] (32 ci used).
// ---------------------------------------------------------------------------
__global__ __launch_bounds__(256) void conv3_mfma_kernel(
    const bf16* __restrict__ xT, const bf16* __restrict__ wo_bf,
    const float* __restrict__ bias, float* __restrict__ out)
{
  __shared__ __align__(16) short smem[27104];
  short* wS = smem;            // 64*296 = 18944
  short* xS = smem + 18944;    // 6*34*40 = 8160

  int tid = threadIdx.x, lane = tid & 63, wave = tid >> 6;
  int m16 = lane & 15, quad = lane >> 4;
  int bid = blockIdx.x;
  int rc = bid & 7, cotile = (bid >> 3) & 3, b = bid >> 5;
  int y0 = rc * 4;

  f32x4 acc[8];
#pragma unroll
  for (int t = 0; t < 8; ++t) acc[t] = (f32x4){0.f, 0.f, 0.f, 0.f};

  for (int ck = 0; ck < 8; ++ck) {
    __syncthreads();
    const bf16* wbase = wo_bf + (size_t)(cotile * 8 + ck) * 18432;
#pragma unroll
    for (int r = 0; r < 9; ++r) {            // 2304 uint4 units
      int u = r * 256 + tid;
      *(uint4*)(wS + (u / 36) * 296 + (u % 36) * 8) = *(const uint4*)(wbase + (size_t)u * 8);
    }
#pragma unroll
    for (int r = 0; r < 3; ++r) {            // 768 units: 6 rows x 32 cols x 4 segs
      int u = r * 256 + tid;
      int pos = u >> 2, seg = u & 3;
      int row = pos >> 5, col = pos & 31;
      int gy = y0 - 1 + row;
      uint4 val = make_uint4(0u, 0u, 0u, 0u);
      if (gy >= 0 && gy < 32)
        val = *(const uint4*)(xT + ((size_t)(b * 1024) + gy * 32 + col) * 256 + ck * 32 + seg * 8);
      *(uint4*)(xS + (row * 34 + col + 1) * 40 + seg * 8) = val;
    }
    if (tid < 48) {                           // zero halo cols (x=-1 and x=32)
      int pos = tid >> 2, seg = tid & 3;
      int row = pos >> 1, side = pos & 1;
      *(uint4*)(xS + (row * 34 + side * 33) * 40 + seg * 8) = make_uint4(0u, 0u, 0u, 0u);
    }
    __syncthreads();
#pragma unroll
    for (int kidx = 0; kidx < 9; ++kidx) {
      int dy = kidx / 3, dx = kidx - dy * 3;
      bf16x8 af = *(const bf16x8*)(wS + (wave * 16 + m16) * 296 + kidx * 32 + quad * 8);
#pragma unroll
      for (int t = 0; t < 8; ++t) {
        int row = (t >> 1) + dy;
        int col = (t & 1) * 16 + m16 + dx;
        bf16x8 bf = *(const bf16x8*)(xS + (row * 34 + col) * 40 + quad * 8);
        acc[t] = __builtin_amdgcn_mfma_f32_16x16x32_bf16(af, bf, acc[t], 0, 0, 0);
      }
    }
  }

  int cob = cotile * 64 + wave * 16 + quad * 4;
#pragma unroll
  for (int i = 0; i < 4; ++i) {
    float bv = bias[cob + i];
#pragma unroll
    for (int t = 0; t < 8; ++t) {
      int y = y0 + (t >> 1), xc = (t & 1) * 16 + m16;
      out[((size_t)(b * 512) + cob + i) * 1024 + y * 32 + xc] = acc[t][i] + bv;
    }
  }
}

// ---------------------------------------------------------------------------
// K2: qkv 1x1 conv as MFMA GEMM 768 x 1024 x 256 per batch.
// Block: 64 c x 128 l. grid (8 ltile, 12 ctile, 8 b).
// Epilogue: per-wave LDS transpose -> coalesced stores (q/k row-major, v d-major).
// ---------------------------------------------------------------------------
__global__ __launch_bounds__(256) void qkv_mfma_kernel(
    const bf16* __restrict__ xT, const float* __restrict__ wq, const float* __restrict__ bias,
    bf16* __restrict__ qT, bf16* __restrict__ kR, bf16* __restrict__ vW)
{
  __shared__ __align__(16) short smem[13824];
  short* aS = smem;            // [64][72]
  short* bS = smem + 4608;     // [128][72]

  int tid = threadIdx.x, lane = tid & 63, wave = tid >> 6;
  int m16 = lane & 15, quad = lane >> 4;
  int l0 = blockIdx.x * 128;
  int ctile = blockIdx.y;
  int b = blockIdx.z;
  int cbase = ctile * 64;

  f32x4 acc[8];
#pragma unroll
  for (int t = 0; t < 8; ++t) acc[t] = (f32x4){0.f, 0.f, 0.f, 0.f};

  for (int ck = 0; ck < 4; ++ck) {
    __syncthreads();
#pragma unroll
    for (int r = 0; r < 4; ++r) {            // A: 64 c x 64 ci from f32, cvt
      int u = r * 256 + tid;                  // 1024 float4 units
      int c = u >> 4, s4 = u & 15;
      float4 v = *(const float4*)(wq + (size_t)(cbase + c) * 256 + ck * 64 + s4 * 4);
      unsigned int p0 = (unsigned int)f2bfbits(v.x) | ((unsigned int)f2bfbits(v.y) << 16);
      unsigned int p1 = (unsigned int)f2bfbits(v.z) | ((unsigned int)f2bfbits(v.w) << 16);
      uint2 u2; u2.x = p0; u2.y = p1;
      *(uint2*)(aS + c * 72 + s4 * 4) = u2;
    }
#pragma unroll
    for (int r = 0; r < 4; ++r) {            // B: 128 l x 64 ci bf16
      int u = r * 256 + tid;                  // 1024 uint4 units
      int l = u >> 3, seg = u & 7;
      *(uint4*)(bS + l * 72 + seg * 8) =
          *(const uint4*)(xT + ((size_t)(b * 1024) + l0 + l) * 256 + ck * 64 + seg * 8);
    }
    __syncthreads();
#pragma unroll
    for (int ks = 0; ks < 2; ++ks) {
      bf16x8 af = *(const bf16x8*)(aS + (wave * 16 + m16) * 72 + ks * 32 + quad * 8);
#pragma unroll
      for (int t = 0; t < 8; ++t) {
        bf16x8 bf = *(const bf16x8*)(bS + (t * 16 + m16) * 72 + ks * 32 + quad * 8);
        acc[t] = __builtin_amdgcn_mfma_f32_16x16x32_bf16(af, bf, acc[t], 0, 0, 0);
      }
    }
  }

  __syncthreads();   // all waves done reading aS/bS; alias as transpose scratch
  short* ldsT = smem + wave * 3072;          // per-wave [128 l][24] (16 c used)
  int cb = cbase + wave * 16;
  bool isq = (ctile < 4);
  float bv[4];
#pragma unroll
  for (int i = 0; i < 4; ++i) bv[i] = bias[cb + quad * 4 + i];
#pragma unroll
  for (int t = 0; t < 8; ++t) {
#pragma unroll
    for (int i = 0; i < 4; ++i) {
      float v = acc[t][i] + bv[i];
      if (isq) v *= 0.17677669529663689f;    // 32^-0.5, pre-rel-logits
      ldsT[(t * 16 + m16) * 24 + quad * 4 + i] = (short)f2bfbits(v);
    }
  }
  // per-wave region, same-wave readback: compiler's lgkmcnt ordering suffices
  if (ctile < 8) {
    bf16* dst = isq ? qT : kR;
    int coff = isq ? cb : cb - 256;
#pragma unroll
    for (int rep = 0; rep < 4; ++rep) {
      int u = rep * 64 + lane;
      int l = u >> 1, half = u & 1;
      int c0 = coff + half * 8;
      int head = b * 8 + (c0 >> 5), d0 = c0 & 31;
      *(uint4*)(dst + ((size_t)head * 1024 + l0 + l) * 32 + d0) =
          *(const uint4*)(ldsT + l * 24 + half * 8);
    }
  } else {
    int dcol = lane >> 2, lg = lane & 3;
    int c2 = (cb - 512) + dcol;
    int head = b * 8 + (c2 >> 5), gd = c2 & 31;
#pragma unroll
    for (int s = 0; s < 4; ++s) {
      union { unsigned int w[4]; uint4 u4; } pk;
#pragma unroll
      for (int p = 0; p < 4; ++p) {
        int j0 = lg * 32 + s * 8 + p * 2;
        unsigned int u0 = (unsigned short)ldsT[j0 * 24 + dcol];
        unsigned int u1 = (unsigned short)ldsT[(j0 + 1) * 24 + dcol];
        pk.w[p] = u0 | (u1 << 16);
      }
      *(uint4*)(vW + ((size_t)head * 32 + gd) * 1024 + l0 + lg * 32 + s * 8) = pk.u4;
    }
  }
}

// ---------------------------------------------------------------------------
// K3: MFMA attention with augmented-K rel logits (unchanged from round 3).
// ---------------------------------------------------------------------------
__global__ __launch_bounds__(256) void attn_mfma_kernel(
    const bf16* __restrict__ qT, const bf16* __restrict__ kR, const bf16* __restrict__ vW,
    const float* __restrict__ krw, const float* __restrict__ krh,
    bf16* __restrict__ attL)
{
  __shared__ __align__(16) char smem[31232];
  short* kaugS  = (short*)smem;
  short* vtS    = (short*)(smem + 13312);
  short* atileS = (short*)(smem + 17920);
  float* krwS   = (float*)smem;
  float* krhS   = krwS + 63 * 33;

  int tid = threadIdx.x;
  int lane = tid & 63, wave = tid >> 6;
  int m16 = lane & 15, quad = lane >> 4;
  int qt = blockIdx.x & 15, head = blockIdx.x >> 4;
  int row0 = qt * 64;
  int b = head >> 3, h = head & 7;

  for (int i = tid; i < 504; i += 256) {
    int row = i >> 3, d0 = (i & 7) * 4;
    float4 a = *(const float4*)(krw + row * 32 + d0);
    krwS[row * 33 + d0 + 0] = a.x; krwS[row * 33 + d0 + 1] = a.y;
    krwS[row * 33 + d0 + 2] = a.z; krwS[row * 33 + d0 + 3] = a.w;
    float4 c = *(const float4*)(krh + row * 32 + d0);
    krhS[row * 33 + d0 + 0] = c.x; krhS[row * 33 + d0 + 1] = c.y;
    krhS[row * 33 + d0 + 2] = c.z; krhS[row * 33 + d0 + 3] = c.w;
  }
  {
    int r = tid >> 2, seg = tid & 3;
    uint4 u = *(const uint4*)(qT + ((size_t)head * 1024 + row0 + r) * 32 + seg * 8);
    *(uint4*)(atileS + r * 104 + seg * 8) = u;
  }
  __syncthreads();

  {
    int r = tid >> 2, jseg = tid & 3;
    int qi = r & 31;
    int qx = qt * 2 + (r >> 5);
    float q32[32];
#pragma unroll
    for (int s4 = 0; s4 < 4; ++s4) {
      uint4 u = ((const uint4*)(atileS + r * 104))[s4];
      q32[s4 * 8 + 0] = blo(u.x); q32[s4 * 8 + 1] = bhi(u.x);
      q32[s4 * 8 + 2] = blo(u.y); q32[s4 * 8 + 3] = bhi(u.y);
      q32[s4 * 8 + 4] = blo(u.z); q32[s4 * 8 + 5] = bhi(u.z);
      q32[s4 * 8 + 6] = blo(u.w); q32[s4 * 8 + 7] = bhi(u.w);
    }
    unsigned int pw[4], ph[4];
#pragma unroll
    for (int jp = 0; jp < 4; ++jp) {
      float sv[4] = {0.f, 0.f, 0.f, 0.f};
#pragma unroll 2
      for (int half = 0; half < 2; ++half) {
        int j = jseg * 8 + jp * 2 + half;
        const float* kw = krwS + (j - qi + 31) * 33;
        const float* kh = krhS + (j - qx + 31) * 33;
        float s1 = 0.f, s2 = 0.f;
#pragma unroll
        for (int d = 0; d < 32; ++d) { s1 += q32[d] * kw[d]; s2 += q32[d] * kh[d]; }
        sv[half] = s1; sv[2 + half] = s2;
      }
      pw[jp] = (unsigned int)f2bfbits(sv[0]) | ((unsigned int)f2bfbits(sv[1]) << 16);
      ph[jp] = (unsigned int)f2bfbits(sv[2]) | ((unsigned int)f2bfbits(sv[3]) << 16);
    }
#pragma unroll
    for (int jp = 0; jp < 4; ++jp) {
      ((unsigned int*)(atileS + r * 104 + 32 + jseg * 8))[jp] = pw[jp];
      ((unsigned int*)(atileS + r * 104 + 64 + jseg * 8))[jp] = ph[jp];
    }
  }
  __syncthreads();

  bf16x8 afrag[3];
  {
    int arow = wave * 16 + m16;
#pragma unroll
    for (int ks = 0; ks < 3; ++ks)
      afrag[ks] = *(const bf16x8*)(atileS + arow * 104 + ks * 32 + quad * 8);
  }

  f32x4 oacc[2];
  oacc[0] = (f32x4){0.f, 0.f, 0.f, 0.f};
  oacc[1] = (f32x4){0.f, 0.f, 0.f, 0.f};
  float rsp[4] = {0.f, 0.f, 0.f, 0.f};
  short* pS = (short*)(smem + 17920) + wave * 1152;

  for (int c = 0; c < 16; ++c) {
    __syncthreads();
    {
      int key = tid >> 2, seg = tid & 3;
      uint4 u = *(const uint4*)(kR + ((size_t)head * 1024 + c * 64 + key) * 32 + seg * 8);
      *(uint4*)(kaugS + key * 104 + seg * 8) = u;
      int gkey = c * 64 + key;
      int mx = gkey & 31, my = gkey >> 5;
      union { short s[16]; uint4 u4[2]; } oh;
#pragma unroll
      for (int e = 0; e < 16; ++e) {
        int j = seg * 16 + e;
        short v;
        if (j < 32) v = (j == mx) ? (short)0x3F80 : (short)0;
        else        v = ((j - 32) == my) ? (short)0x3F80 : (short)0;
        oh.s[e] = v;
      }
      ((uint4*)(kaugS + key * 104 + 32 + seg * 16))[0] = oh.u4[0];
      *((uint4*)(kaugS + key * 104 + 32 + seg * 16) + 1) = oh.u4[1];
    }
    {
      int d = tid >> 3, kseg = tid & 7;
      uint4 u = *(const uint4*)(vW + (size_t)head * 32768 + d * 1024 + c * 64 + kseg * 8);
      *(uint4*)(vtS + d * 72 + kseg * 8) = u;
    }
    __syncthreads();

    f32x4 sacc[4];
#pragma unroll
    for (int t = 0; t < 4; ++t) sacc[t] = (f32x4){0.f, 0.f, 0.f, 0.f};
#pragma unroll
    for (int t = 0; t < 4; ++t) {
#pragma unroll
      for (int ks = 0; ks < 3; ++ks) {
        bf16x8 bfK = *(const bf16x8*)(kaugS + (t * 16 + m16) * 104 + ks * 32 + quad * 8);
        sacc[t] = __builtin_amdgcn_mfma_f32_16x16x32_bf16(afrag[ks], bfK, sacc[t], 0, 0, 0);
      }
    }
#pragma unroll
    for (int t = 0; t < 4; ++t) {
#pragma unroll
      for (int i = 0; i < 4; ++i) {
        float e = __expf(sacc[t][i]);
        rsp[i] += e;
        pS[(quad * 4 + i) * 72 + t * 16 + m16] = (short)f2bfbits(e);
      }
    }
#pragma unroll
    for (int ks2 = 0; ks2 < 2; ++ks2) {
      bf16x8 pf = *(const bf16x8*)(pS + m16 * 72 + ks2 * 32 + quad * 8);
#pragma unroll
      for (int dt = 0; dt < 2; ++dt) {
        bf16x8 vf = *(const bf16x8*)(vtS + (dt * 16 + m16) * 72 + ks2 * 32 + quad * 8);
        oacc[dt] = __builtin_amdgcn_mfma_f32_16x16x32_bf16(pf, vf, oacc[dt], 0, 0, 0);
      }
    }
  }

#pragma unroll
  for (int off = 1; off < 16; off <<= 1)
#pragma unroll
    for (int i = 0; i < 4; ++i) rsp[i] += __shfl_xor(rsp[i], off, 64);
#pragma unroll
  for (int i = 0; i < 4; ++i) {
    float invs = 1.0f / rsp[i];
    int grow = row0 + wave * 16 + quad * 4 + i;
#pragma unroll
    for (int dt = 0; dt < 2; ++dt) {
      attL[((size_t)b * 1024 + grow) * 256 + h * 32 + dt * 16 + m16] =
          __float2bfloat16(oacc[dt][i] * invs);
    }
  }
}

// ---------------------------------------------------------------------------
// K4: 1x1 conv on attention result -> output channels 256..511.
// ---------------------------------------------------------------------------
__global__ __launch_bounds__(256) void attnout_kernel(
    const bf16* __restrict__ attL, const float* __restrict__ w, const float* __restrict__ bias,
    float* __restrict__ out)
{
  __shared__ __align__(16) float aL[1024];
  int tid = threadIdx.x;
  int lg = blockIdx.x & 255;
  int b  = blockIdx.x >> 8;
  int l0 = lg * 4;
#pragma unroll
  for (int rep = 0; rep < 4; ++rep) {
    int idx = rep * 256 + tid;
    aL[idx] = bf2f(attL[((size_t)b * 1024 + l0) * 256 + idx]);
  }
  __syncthreads();

  float acc[4] = {0.f, 0.f, 0.f, 0.f};
  const float* wrow = w + (size_t)tid * 256;
  for (int c8 = 0; c8 < 32; ++c8) {
    float4 wa = ((const float4*)wrow)[c8 * 2];
    float4 wb = ((const float4*)wrow)[c8 * 2 + 1];
    float wv[8] = {wa.x, wa.y, wa.z, wa.w, wb.x, wb.y, wb.z, wb.w};
#pragma unroll
    for (int e = 0; e < 8; ++e) {
#pragma unroll
      for (int j = 0; j < 4; ++j) acc[j] += wv[e] * aL[j * 256 + c8 * 8 + e];
    }
  }
  float bv = bias[tid];
  size_t obase = ((size_t)(b * 512 + 256 + tid)) * 1024 + l0;
#pragma unroll
  for (int j = 0; j < 4; ++j) out[obase + j] = acc[j] + bv;
}

// ---------------------------------------------------------------------------
extern "C" void kernel_launch(void* const* d_in, const int* in_sizes, int n_in,
                              void* d_out, int out_size, void* d_ws, size_t ws_size,
                              hipStream_t stream) {
  const float* x      = (const float*)d_in[0];
  const float* w_qkv  = (const float*)d_in[1];
  const float* b_qkv  = (const float*)d_in[2];
  const float* w_attn = (const float*)d_in[3];
  const float* b_attn = (const float*)d_in[4];
  const float* w_out  = (const float*)d_in[5];
  const float* b_out  = (const float*)d_in[6];
  const float* krw    = (const float*)d_in[7];
  const float* krh    = (const float*)d_in[8];
  float* out = (float*)d_out;

  bf16* ws    = (bf16*)d_ws;
  bf16* xT    = ws;                 // [0, 2,097,152)   dead after qkv
  bf16* attL  = ws;                 // alias of xT      (attn -> attnout)
  bf16* wo_bf = ws + 2097152;       // [2,097,152, 2,686,976)  dead after conv3
  bf16* qT    = ws + 2097152;       // [2,097,152, 4,194,304)  written after conv3
  bf16* kR    = ws + 4194304;       // [4,194,304, 6,291,456)
  bf16* vW    = ws + 6291456;       // [6,291,456, 8,388,608)  exact 16 MB fit

  prep_kernel<<<dim3(2084), 256, 0, stream>>>(x, w_out, xT, wo_bf);
  conv3_mfma_kernel<<<dim3(256), 256, 0, stream>>>(xT, wo_bf, b_out, out);
  qkv_mfma_kernel<<<dim3(8, 12, 8), 256, 0, stream>>>(xT, w_qkv, b_qkv, qT, kR, vW);
  attn_mfma_kernel<<<dim3(1024), 256, 0, stream>>>(qT, kR, vW, krw, krh, attL);
  attnout_kernel<<<dim3(2048), 256, 0, stream>>>(attL, w_attn, b_attn, out);
}

// Round 5
// 183.690 us; speedup vs baseline: 7.8325x; 1.2978x over previous
//
#include <hip/hip_runtime.h>
#include <hip/hip_bf16.h>

// AttentionConv2d: B=8, C_IN=256, H=W=32 (HW=1024), DK=DV=256, NH=8, DKH=DVH=32,
// C_OUT=512, 3x3 conv pad=1. fp32 storage in/out; bf16 intermediates + MFMA.
//
// Workspace (bf16 elements, EXACTLY 16 MB = 8,388,608 bf16 — proven safe size):
//   xT    [8 b][1024 l][256 ci]  @ 0          (dead after qkv)  } aliased later by
//   attL  [8 b][1024 l][256 ch]  @ 0          (attn -> attnout) } each other
//   wo_bf chunk-blocked          @ 2,097,152  (589,824; dead after conv3)
//   qT    [64 head][1024][32]    @ 2,097,152  (written by qkv AFTER conv3 -> safe alias)
//   kR    [64 head][1024][32]    @ 4,194,304
//   vW    [64 head][32][1024]    @ 6,291,456  (ends exactly 8,388,608)
// Kernel order: prep -> conv3 -> qkv -> attn -> attnout (stream-serial).

typedef __hip_bfloat16 bf16;
typedef __attribute__((ext_vector_type(8))) short bf16x8;
typedef __attribute__((ext_vector_type(4))) float f32x4;

__device__ __forceinline__ float bf2f(bf16 v) { return __bfloat162float(v); }
__device__ __forceinline__ float blo(unsigned int v) { return __uint_as_float(v << 16); }
__device__ __forceinline__ float bhi(unsigned int v) { return __uint_as_float(v & 0xffff0000u); }
__device__ __forceinline__ unsigned short f2bfbits(float f) {
  union { bf16 h; unsigned short u; } cv; cv.h = __float2bfloat16(f); return cv.u;
}

// ---------------------------------------------------------------------------
// K0: prep — xT transpose to bf16 + w_out bf16 chunk-blocked.
// blocks 0..2047: xT; 2048..2083: w_out. grid 2084.
// w_out_bf layout: [(co>>6)*8 + (ci>>5)][co&63][kidx 9][ci&31]  (18432 bf16/chunkblk)
// ---------------------------------------------------------------------------
__global__ __launch_bounds__(256) void prep_kernel(
    const float* __restrict__ x, const float* __restrict__ wout,
    bf16* __restrict__ xT, bf16* __restrict__ wo_bf)
{
  int bid = blockIdx.x, tid = threadIdx.x;
  if (bid < 2048) {
    __shared__ float t[32 * 33];
    int b = bid >> 8, rem = bid & 255;
    int ci0 = (rem >> 5) * 32, l0 = (rem & 31) * 32;
    {
      int ciL = tid >> 3, lL4 = (tid & 7) * 4;
      float4 v = *(const float4*)(x + (size_t)(b * 256 + ci0 + ciL) * 1024 + l0 + lL4);
      t[ciL * 33 + lL4 + 0] = v.x; t[ciL * 33 + lL4 + 1] = v.y;
      t[ciL * 33 + lL4 + 2] = v.z; t[ciL * 33 + lL4 + 3] = v.w;
    }
    __syncthreads();
    {
      int lL = tid >> 3, cS = (tid & 7) * 4;
      unsigned int p0 = (unsigned int)f2bfbits(t[(cS + 0) * 33 + lL]) |
                        ((unsigned int)f2bfbits(t[(cS + 1) * 33 + lL]) << 16);
      unsigned int p1 = (unsigned int)f2bfbits(t[(cS + 2) * 33 + lL]) |
                        ((unsigned int)f2bfbits(t[(cS + 3) * 33 + lL]) << 16);
      uint2 u2; u2.x = p0; u2.y = p1;
      *(uint2*)(xT + ((size_t)(b * 1024) + l0 + lL) * 256 + ci0 + cS) = u2;
    }
  } else {
    int t0 = (bid - 2048) * 256 + tid;       // 0..9215
#pragma unroll
    for (int s = 0; s < 8; ++s) {
      int u = s * 9216 + t0;                 // dst uint4 index 0..73727
      int chunkblk = u / 2304;
      int within = u - chunkblk * 2304;
      int co63 = within / 36;
      int r = within - co63 * 36;            // kidx*4 + cig
      int kidx = r >> 2, cig = r & 3;
      int co = (chunkblk >> 3) * 64 + co63;
      int ci = (chunkblk & 7) * 32 + cig * 8;
      union { unsigned short h[8]; uint4 u4; } pk;
#pragma unroll
      for (int j = 0; j < 8; ++j)
        pk.h[j] = f2bfbits(wout[(size_t)(co * 256 + ci + j) * 9 + kidx]);
      *(uint4*)(wo_bf + (size_t)u * 8) = pk.u4;
    }
  }
}

// ---------------------------------------------------------------------------
// K1: 3x3 conv 256->256 via 9 shift-GEMMs, MFMA bf16.
// Block: 64 co x 128 spatial (4 rows). grid 256 = b(8) x cotile(4) x rowchunk(8).
// LDS: wS[64 co][296] (288 = 9 kidx * 32 ci), xS[6 rows][34 cols][40] (32 ci used).
// ---------------------------------------------------------------------------
__global__ __launch_bounds__(256) void conv3_mfma_kernel(
    const bf16* __restrict__ xT, const bf16* __restrict__ wo_bf,
    const float* __restrict__ bias, float* __restrict__ out)
{
  __shared__ __align__(16) short smem[27104];
  short* wS = smem;            // 64*296 = 18944
  short* xS = smem + 18944;    // 6*34*40 = 8160

  int tid = threadIdx.x, lane = tid & 63, wave = tid >> 6;
  int m16 = lane & 15, quad = lane >> 4;
  int bid = blockIdx.x;
  int rc = bid & 7, cotile = (bid >> 3) & 3, b = bid >> 5;
  int y0 = rc * 4;

  f32x4 acc[8];
#pragma unroll
  for (int t = 0; t < 8; ++t) acc[t] = (f32x4){0.f, 0.f, 0.f, 0.f};

  for (int ck = 0; ck < 8; ++ck) {
    __syncthreads();
    const bf16* wbase = wo_bf + (size_t)(cotile * 8 + ck) * 18432;
#pragma unroll
    for (int r = 0; r < 9; ++r) {            // 2304 uint4 units
      int u = r * 256 + tid;
      *(uint4*)(wS + (u / 36) * 296 + (u % 36) * 8) = *(const uint4*)(wbase + (size_t)u * 8);
    }
#pragma unroll
    for (int r = 0; r < 3; ++r) {            // 768 units: 6 rows x 32 cols x 4 segs
      int u = r * 256 + tid;
      int pos = u >> 2, seg = u & 3;
      int row = pos >> 5, col = pos & 31;
      int gy = y0 - 1 + row;
      uint4 val = make_uint4(0u, 0u, 0u, 0u);
      if (gy >= 0 && gy < 32)
        val = *(const uint4*)(xT + ((size_t)(b * 1024) + gy * 32 + col) * 256 + ck * 32 + seg * 8);
      *(uint4*)(xS + (row * 34 + col + 1) * 40 + seg * 8) = val;
    }
    if (tid < 48) {                           // zero halo cols (x=-1 and x=32)
      int pos = tid >> 2, seg = tid & 3;
      int row = pos >> 1, side = pos & 1;
      *(uint4*)(xS + (row * 34 + side * 33) * 40 + seg * 8) = make_uint4(0u, 0u, 0u, 0u);
    }
    __syncthreads();
#pragma unroll
    for (int kidx = 0; kidx < 9; ++kidx) {
      int dy = kidx / 3, dx = kidx - dy * 3;
      bf16x8 af = *(const bf16x8*)(wS + (wave * 16 + m16) * 296 + kidx * 32 + quad * 8);
#pragma unroll
      for (int t = 0; t < 8; ++t) {
        int row = (t >> 1) + dy;
        int col = (t & 1) * 16 + m16 + dx;
        bf16x8 bf = *(const bf16x8*)(xS + (row * 34 + col) * 40 + quad * 8);
        acc[t] = __builtin_amdgcn_mfma_f32_16x16x32_bf16(af, bf, acc[t], 0, 0, 0);
      }
    }
  }

  int cob = cotile * 64 + wave * 16 + quad * 4;
#pragma unroll
  for (int i = 0; i < 4; ++i) {
    float bv = bias[cob + i];
#pragma unroll
    for (int t = 0; t < 8; ++t) {
      int y = y0 + (t >> 1), xc = (t & 1) * 16 + m16;
      out[((size_t)(b * 512) + cob + i) * 1024 + y * 32 + xc] = acc[t][i] + bv;
    }
  }
}

// ---------------------------------------------------------------------------
// K2: qkv 1x1 conv as MFMA GEMM 768 x 1024 x 256 per batch.
// Block: 64 c x 128 l. grid (8 ltile, 12 ctile, 8 b).
// Epilogue: per-wave LDS transpose -> coalesced stores (q/k row-major, v d-major).
// ---------------------------------------------------------------------------
__global__ __launch_bounds__(256) void qkv_mfma_kernel(
    const bf16* __restrict__ xT, const float* __restrict__ wq, const float* __restrict__ bias,
    bf16* __restrict__ qT, bf16* __restrict__ kR, bf16* __restrict__ vW)
{
  __shared__ __align__(16) short smem[13824];
  short* aS = smem;            // [64][72]
  short* bS = smem + 4608;     // [128][72]

  int tid = threadIdx.x, lane = tid & 63, wave = tid >> 6;
  int m16 = lane & 15, quad = lane >> 4;
  int l0 = blockIdx.x * 128;
  int ctile = blockIdx.y;
  int b = blockIdx.z;
  int cbase = ctile * 64;

  f32x4 acc[8];
#pragma unroll
  for (int t = 0; t < 8; ++t) acc[t] = (f32x4){0.f, 0.f, 0.f, 0.f};

  for (int ck = 0; ck < 4; ++ck) {
    __syncthreads();
#pragma unroll
    for (int r = 0; r < 4; ++r) {            // A: 64 c x 64 ci from f32, cvt
      int u = r * 256 + tid;                  // 1024 float4 units
      int c = u >> 4, s4 = u & 15;
      float4 v = *(const float4*)(wq + (size_t)(cbase + c) * 256 + ck * 64 + s4 * 4);
      unsigned int p0 = (unsigned int)f2bfbits(v.x) | ((unsigned int)f2bfbits(v.y) << 16);
      unsigned int p1 = (unsigned int)f2bfbits(v.z) | ((unsigned int)f2bfbits(v.w) << 16);
      uint2 u2; u2.x = p0; u2.y = p1;
      *(uint2*)(aS + c * 72 + s4 * 4) = u2;
    }
#pragma unroll
    for (int r = 0; r < 4; ++r) {            // B: 128 l x 64 ci bf16
      int u = r * 256 + tid;                  // 1024 uint4 units
      int l = u >> 3, seg = u & 7;
      *(uint4*)(bS + l * 72 + seg * 8) =
          *(const uint4*)(xT + ((size_t)(b * 1024) + l0 + l) * 256 + ck * 64 + seg * 8);
    }
    __syncthreads();
#pragma unroll
    for (int ks = 0; ks < 2; ++ks) {
      bf16x8 af = *(const bf16x8*)(aS + (wave * 16 + m16) * 72 + ks * 32 + quad * 8);
#pragma unroll
      for (int t = 0; t < 8; ++t) {
        bf16x8 bf = *(const bf16x8*)(bS + (t * 16 + m16) * 72 + ks * 32 + quad * 8);
        acc[t] = __builtin_amdgcn_mfma_f32_16x16x32_bf16(af, bf, acc[t], 0, 0, 0);
      }
    }
  }

  __syncthreads();   // all waves done reading aS/bS; alias as transpose scratch
  short* ldsT = smem + wave * 3072;          // per-wave [128 l][24] (16 c used)
  int cb = cbase + wave * 16;
  bool isq = (ctile < 4);
  float bv[4];
#pragma unroll
  for (int i = 0; i < 4; ++i) bv[i] = bias[cb + quad * 4 + i];
#pragma unroll
  for (int t = 0; t < 8; ++t) {
#pragma unroll
    for (int i = 0; i < 4; ++i) {
      float v = acc[t][i] + bv[i];
      if (isq) v *= 0.17677669529663689f;    // 32^-0.5, pre-rel-logits
      ldsT[(t * 16 + m16) * 24 + quad * 4 + i] = (short)f2bfbits(v);
    }
  }
  // per-wave region, same-wave readback: compiler's lgkmcnt ordering suffices
  if (ctile < 8) {
    bf16* dst = isq ? qT : kR;
    int coff = isq ? cb : cb - 256;
#pragma unroll
    for (int rep = 0; rep < 4; ++rep) {
      int u = rep * 64 + lane;
      int l = u >> 1, half = u & 1;
      int c0 = coff + half * 8;
      int head = b * 8 + (c0 >> 5), d0 = c0 & 31;
      *(uint4*)(dst + ((size_t)head * 1024 + l0 + l) * 32 + d0) =
          *(const uint4*)(ldsT + l * 24 + half * 8);
    }
  } else {
    int dcol = lane >> 2, lg = lane & 3;
    int c2 = (cb - 512) + dcol;
    int head = b * 8 + (c2 >> 5), gd = c2 & 31;
#pragma unroll
    for (int s = 0; s < 4; ++s) {
      union { unsigned int w[4]; uint4 u4; } pk;
#pragma unroll
      for (int p = 0; p < 4; ++p) {
        int j0 = lg * 32 + s * 8 + p * 2;
        unsigned int u0 = (unsigned short)ldsT[j0 * 24 + dcol];
        unsigned int u1 = (unsigned short)ldsT[(j0 + 1) * 24 + dcol];
        pk.w[p] = u0 | (u1 << 16);
      }
      *(uint4*)(vW + ((size_t)head * 32 + gd) * 1024 + l0 + lg * 32 + s * 8) = pk.u4;
    }
  }
}

// ---------------------------------------------------------------------------
// K3: MFMA attention with augmented-K rel logits (unchanged).
// ---------------------------------------------------------------------------
__global__ __launch_bounds__(256) void attn_mfma_kernel(
    const bf16* __restrict__ qT, const bf16* __restrict__ kR, const bf16* __restrict__ vW,
    const float* __restrict__ krw, const float* __restrict__ krh,
    bf16* __restrict__ attL)
{
  __shared__ __align__(16) char smem[31232];
  short* kaugS  = (short*)smem;
  short* vtS    = (short*)(smem + 13312);
  short* atileS = (short*)(smem + 17920);
  float* krwS   = (float*)smem;
  float* krhS   = krwS + 63 * 33;

  int tid = threadIdx.x;
  int lane = tid & 63, wave = tid >> 6;
  int m16 = lane & 15, quad = lane >> 4;
  int qt = blockIdx.x & 15, head = blockIdx.x >> 4;
  int row0 = qt * 64;
  int b = head >> 3, h = head & 7;

  for (int i = tid; i < 504; i += 256) {
    int row = i >> 3, d0 = (i & 7) * 4;
    float4 a = *(const float4*)(krw + row * 32 + d0);
    krwS[row * 33 + d0 + 0] = a.x; krwS[row * 33 + d0 + 1] = a.y;
    krwS[row * 33 + d0 + 2] = a.z; krwS[row * 33 + d0 + 3] = a.w;
    float4 c = *(const float4*)(krh + row * 32 + d0);
    krhS[row * 33 + d0 + 0] = c.x; krhS[row * 33 + d0 + 1] = c.y;
    krhS[row * 33 + d0 + 2] = c.z; krhS[row * 33 + d0 + 3] = c.w;
  }
  {
    int r = tid >> 2, seg = tid & 3;
    uint4 u = *(const uint4*)(qT + ((size_t)head * 1024 + row0 + r) * 32 + seg * 8);
    *(uint4*)(atileS + r * 104 + seg * 8) = u;
  }
  __syncthreads();

  {
    int r = tid >> 2, jseg = tid & 3;
    int qi = r & 31;
    int qx = qt * 2 + (r >> 5);
    float q32[32];
#pragma unroll
    for (int s4 = 0; s4 < 4; ++s4) {
      uint4 u = ((const uint4*)(atileS + r * 104))[s4];
      q32[s4 * 8 + 0] = blo(u.x); q32[s4 * 8 + 1] = bhi(u.x);
      q32[s4 * 8 + 2] = blo(u.y); q32[s4 * 8 + 3] = bhi(u.y);
      q32[s4 * 8 + 4] = blo(u.z); q32[s4 * 8 + 5] = bhi(u.z);
      q32[s4 * 8 + 6] = blo(u.w); q32[s4 * 8 + 7] = bhi(u.w);
    }
    unsigned int pw[4], ph[4];
#pragma unroll
    for (int jp = 0; jp < 4; ++jp) {
      float sv[4] = {0.f, 0.f, 0.f, 0.f};
#pragma unroll 2
      for (int half = 0; half < 2; ++half) {
        int j = jseg * 8 + jp * 2 + half;
        const float* kw = krwS + (j - qi + 31) * 33;
        const float* kh = krhS + (j - qx + 31) * 33;
        float s1 = 0.f, s2 = 0.f;
#pragma unroll
        for (int d = 0; d < 32; ++d) { s1 += q32[d] * kw[d]; s2 += q32[d] * kh[d]; }
        sv[half] = s1; sv[2 + half] = s2;
      }
      pw[jp] = (unsigned int)f2bfbits(sv[0]) | ((unsigned int)f2bfbits(sv[1]) << 16);
      ph[jp] = (unsigned int)f2bfbits(sv[2]) | ((unsigned int)f2bfbits(sv[3]) << 16);
    }
#pragma unroll
    for (int jp = 0; jp < 4; ++jp) {
      ((unsigned int*)(atileS + r * 104 + 32 + jseg * 8))[jp] = pw[jp];
      ((unsigned int*)(atileS + r * 104 + 64 + jseg * 8))[jp] = ph[jp];
    }
  }
  __syncthreads();

  bf16x8 afrag[3];
  {
    int arow = wave * 16 + m16;
#pragma unroll
    for (int ks = 0; ks < 3; ++ks)
      afrag[ks] = *(const bf16x8*)(atileS + arow * 104 + ks * 32 + quad * 8);
  }

  f32x4 oacc[2];
  oacc[0] = (f32x4){0.f, 0.f, 0.f, 0.f};
  oacc[1] = (f32x4){0.f, 0.f, 0.f, 0.f};
  float rsp[4] = {0.f, 0.f, 0.f, 0.f};
  short* pS = (short*)(smem + 17920) + wave * 1152;

  for (int c = 0; c < 16; ++c) {
    __syncthreads();
    {
      int key = tid >> 2, seg = tid & 3;
      uint4 u = *(const uint4*)(kR + ((size_t)head * 1024 + c * 64 + key) * 32 + seg * 8);
      *(uint4*)(kaugS + key * 104 + seg * 8) = u;
      int gkey = c * 64 + key;
      int mx = gkey & 31, my = gkey >> 5;
      union { short s[16]; uint4 u4[2]; } oh;
#pragma unroll
      for (int e = 0; e < 16; ++e) {
        int j = seg * 16 + e;
        short v;
        if (j < 32) v = (j == mx) ? (short)0x3F80 : (short)0;
        else        v = ((j - 32) == my) ? (short)0x3F80 : (short)0;
        oh.s[e] = v;
      }
      ((uint4*)(kaugS + key * 104 + 32 + seg * 16))[0] = oh.u4[0];
      *((uint4*)(kaugS + key * 104 + 32 + seg * 16) + 1) = oh.u4[1];
    }
    {
      int d = tid >> 3, kseg = tid & 7;
      uint4 u = *(const uint4*)(vW + (size_t)head * 32768 + d * 1024 + c * 64 + kseg * 8);
      *(uint4*)(vtS + d * 72 + kseg * 8) = u;
    }
    __syncthreads();

    f32x4 sacc[4];
#pragma unroll
    for (int t = 0; t < 4; ++t) sacc[t] = (f32x4){0.f, 0.f, 0.f, 0.f};
#pragma unroll
    for (int t = 0; t < 4; ++t) {
#pragma unroll
      for (int ks = 0; ks < 3; ++ks) {
        bf16x8 bfK = *(const bf16x8*)(kaugS + (t * 16 + m16) * 104 + ks * 32 + quad * 8);
        sacc[t] = __builtin_amdgcn_mfma_f32_16x16x32_bf16(afrag[ks], bfK, sacc[t], 0, 0, 0);
      }
    }
#pragma unroll
    for (int t = 0; t < 4; ++t) {
#pragma unroll
      for (int i = 0; i < 4; ++i) {
        float e = __expf(sacc[t][i]);
        rsp[i] += e;
        pS[(quad * 4 + i) * 72 + t * 16 + m16] = (short)f2bfbits(e);
      }
    }
#pragma unroll
    for (int ks2 = 0; ks2 < 2; ++ks2) {
      bf16x8 pf = *(const bf16x8*)(pS + m16 * 72 + ks2 * 32 + quad * 8);
#pragma unroll
      for (int dt = 0; dt < 2; ++dt) {
        bf16x8 vf = *(const bf16x8*)(vtS + (dt * 16 + m16) * 72 + ks2 * 32 + quad * 8);
        oacc[dt] = __builtin_amdgcn_mfma_f32_16x16x32_bf16(pf, vf, oacc[dt], 0, 0, 0);
      }
    }
  }

#pragma unroll
  for (int off = 1; off < 16; off <<= 1)
#pragma unroll
    for (int i = 0; i < 4; ++i) rsp[i] += __shfl_xor(rsp[i], off, 64);
#pragma unroll
  for (int i = 0; i < 4; ++i) {
    float invs = 1.0f / rsp[i];
    int grow = row0 + wave * 16 + quad * 4 + i;
#pragma unroll
    for (int dt = 0; dt < 2; ++dt) {
      attL[((size_t)b * 1024 + grow) * 256 + h * 32 + dt * 16 + m16] =
          __float2bfloat16(oacc[dt][i] * invs);
    }
  }
}

// ---------------------------------------------------------------------------
// K4: attnout 1x1 conv as MFMA GEMM 256 x 1024 x 256 per batch.
// Block: 64 co x 128 l. grid (8 ltile, 4 cotile, 8 b) = 256 blocks.
// Epilogue: direct fp32 stores, C/D-layout -> 64B-contiguous runs along l.
// ---------------------------------------------------------------------------
__global__ __launch_bounds__(256) void attnout_mfma_kernel(
    const bf16* __restrict__ attL, const float* __restrict__ w, const float* __restrict__ bias,
    float* __restrict__ out)
{
  __shared__ __align__(16) short smem[13824];
  short* aS = smem;            // [64 co][72]
  short* bS = smem + 4608;     // [128 l][72]

  int tid = threadIdx.x, lane = tid & 63, wave = tid >> 6;
  int m16 = lane & 15, quad = lane >> 4;
  int l0 = blockIdx.x * 128;
  int cotile = blockIdx.y;
  int b = blockIdx.z;
  int cbase = cotile * 64;

  f32x4 acc[8];
#pragma unroll
  for (int t = 0; t < 8; ++t) acc[t] = (f32x4){0.f, 0.f, 0.f, 0.f};

  for (int ck = 0; ck < 4; ++ck) {
    __syncthreads();
#pragma unroll
    for (int r = 0; r < 4; ++r) {            // A: 64 co x 64 ci from f32, cvt
      int u = r * 256 + tid;                  // 1024 float4 units
      int c = u >> 4, s4 = u & 15;
      float4 v = *(const float4*)(w + (size_t)(cbase + c) * 256 + ck * 64 + s4 * 4);
      unsigned int p0 = (unsigned int)f2bfbits(v.x) | ((unsigned int)f2bfbits(v.y) << 16);
      unsigned int p1 = (unsigned int)f2bfbits(v.z) | ((unsigned int)f2bfbits(v.w) << 16);
      uint2 u2; u2.x = p0; u2.y = p1;
      *(uint2*)(aS + c * 72 + s4 * 4) = u2;
    }
#pragma unroll
    for (int r = 0; r < 4; ++r) {            // B: 128 l x 64 ci bf16
      int u = r * 256 + tid;                  // 1024 uint4 units
      int l = u >> 3, seg = u & 7;
      *(uint4*)(bS + l * 72 + seg * 8) =
          *(const uint4*)(attL + ((size_t)(b * 1024) + l0 + l) * 256 + ck * 64 + seg * 8);
    }
    __syncthreads();
#pragma unroll
    for (int ks = 0; ks < 2; ++ks) {
      bf16x8 af = *(const bf16x8*)(aS + (wave * 16 + m16) * 72 + ks * 32 + quad * 8);
#pragma unroll
      for (int t = 0; t < 8; ++t) {
        bf16x8 bf = *(const bf16x8*)(bS + (t * 16 + m16) * 72 + ks * 32 + quad * 8);
        acc[t] = __builtin_amdgcn_mfma_f32_16x16x32_bf16(af, bf, acc[t], 0, 0, 0);
      }
    }
  }

  int co = cbase + wave * 16 + quad * 4;
#pragma unroll
  for (int i = 0; i < 4; ++i) {
    float bv = bias[co + i];
    size_t obase = ((size_t)(b * 512) + 256 + co + i) * 1024 + l0;
#pragma unroll
    for (int t = 0; t < 8; ++t)
      out[obase + t * 16 + m16] = acc[t][i] + bv;
  }
}

// ---------------------------------------------------------------------------
extern "C" void kernel_launch(void* const* d_in, const int* in_sizes, int n_in,
                              void* d_out, int out_size, void* d_ws, size_t ws_size,
                              hipStream_t stream) {
  const float* x      = (const float*)d_in[0];
  const float* w_qkv  = (const float*)d_in[1];
  const float* b_qkv  = (const float*)d_in[2];
  const float* w_attn = (const float*)d_in[3];
  const float* b_attn = (const float*)d_in[4];
  const float* w_out  = (const float*)d_in[5];
  const float* b_out  = (const float*)d_in[6];
  const float* krw    = (const float*)d_in[7];
  const float* krh    = (const float*)d_in[8];
  float* out = (float*)d_out;

  bf16* ws    = (bf16*)d_ws;
  bf16* xT    = ws;                 // [0, 2,097,152)   dead after qkv
  bf16* attL  = ws;                 // alias of xT      (attn -> attnout)
  bf16* wo_bf = ws + 2097152;       // [2,097,152, 2,686,976)  dead after conv3
  bf16* qT    = ws + 2097152;       // [2,097,152, 4,194,304)  written after conv3
  bf16* kR    = ws + 4194304;       // [4,194,304, 6,291,456)
  bf16* vW    = ws + 6291456;       // [6,291,456, 8,388,608)  exact 16 MB fit

  prep_kernel<<<dim3(2084), 256, 0, stream>>>(x, w_out, xT, wo_bf);
  conv3_mfma_kernel<<<dim3(256), 256, 0, stream>>>(xT, wo_bf, b_out, out);
  qkv_mfma_kernel<<<dim3(8, 12, 8), 256, 0, stream>>>(xT, w_qkv, b_qkv, qT, kR, vW);
  attn_mfma_kernel<<<dim3(1024), 256, 0, stream>>>(qT, kR, vW, krw, krh, attL);
  attnout_mfma_kernel<<<dim3(8, 4, 8), 256, 0, stream>>>(attL, w_attn, b_attn, out);
}

// Round 6
// 176.136 us; speedup vs baseline: 8.1685x; 1.0429x over previous
//
#include <hip/hip_runtime.h>
#include <hip/hip_bf16.h>

// AttentionConv2d: B=8, C_IN=256, H=W=32 (HW=1024), DK=DV=256, NH=8, DKH=DVH=32,
// C_OUT=512, 3x3 conv pad=1. fp32 storage in/out; bf16 intermediates + MFMA.
//
// Workspace (bf16 elements, EXACTLY 16 MB = 8,388,608 bf16 — proven safe size):
//   xT    [8 b][1024 l][256 ci]  @ 0          (dead after qkv)  } aliased later by
//   attL  [8 b][1024 l][256 ch]  @ 0          (attn -> attnout) } each other
//   wo_bf chunk-blocked          @ 2,097,152  (589,824; dead after conv3)
//   qT    [64 head][1024][32]    @ 2,097,152  (written by qkv AFTER conv3 -> safe alias)
//   kR    [64 head][1024][32]    @ 4,194,304
//   vW    [64 head][32][1024]    @ 6,291,456  (ends exactly 8,388,608)
// Kernel order: prep -> conv3 -> qkv -> attn -> attnout (stream-serial).

typedef __hip_bfloat16 bf16;
typedef __attribute__((ext_vector_type(8))) short bf16x8;
typedef __attribute__((ext_vector_type(4))) float f32x4;

__device__ __forceinline__ float bf2f(bf16 v) { return __bfloat162float(v); }
__device__ __forceinline__ float blo(unsigned int v) { return __uint_as_float(v << 16); }
__device__ __forceinline__ float bhi(unsigned int v) { return __uint_as_float(v & 0xffff0000u); }
__device__ __forceinline__ unsigned short f2bfbits(float f) {
  union { bf16 h; unsigned short u; } cv; cv.h = __float2bfloat16(f); return cv.u;
}
// cheap round-to-nearest (ties away): 2 VALU ops vs ~4 for RNE; <=1 ulp diff.
__device__ __forceinline__ short f2bfr(float f) {
  return (short)((__float_as_uint(f) + 0x8000u) >> 16);
}

// ---------------------------------------------------------------------------
// K0: prep — xT transpose to bf16 + w_out bf16 chunk-blocked.
// blocks 0..2047: xT; 2048..2083: w_out. grid 2084.
// w_out_bf layout: [(co>>6)*8 + (ci>>5)][co&63][kidx 9][ci&31]  (18432 bf16/chunkblk)
// ---------------------------------------------------------------------------
__global__ __launch_bounds__(256) void prep_kernel(
    const float* __restrict__ x, const float* __restrict__ wout,
    bf16* __restrict__ xT, bf16* __restrict__ wo_bf)
{
  int bid = blockIdx.x, tid = threadIdx.x;
  if (bid < 2048) {
    __shared__ float t[32 * 33];
    int b = bid >> 8, rem = bid & 255;
    int ci0 = (rem >> 5) * 32, l0 = (rem & 31) * 32;
    {
      int ciL = tid >> 3, lL4 = (tid & 7) * 4;
      float4 v = *(const float4*)(x + (size_t)(b * 256 + ci0 + ciL) * 1024 + l0 + lL4);
      t[ciL * 33 + lL4 + 0] = v.x; t[ciL * 33 + lL4 + 1] = v.y;
      t[ciL * 33 + lL4 + 2] = v.z; t[ciL * 33 + lL4 + 3] = v.w;
    }
    __syncthreads();
    {
      int lL = tid >> 3, cS = (tid & 7) * 4;
      unsigned int p0 = (unsigned int)f2bfbits(t[(cS + 0) * 33 + lL]) |
                        ((unsigned int)f2bfbits(t[(cS + 1) * 33 + lL]) << 16);
      unsigned int p1 = (unsigned int)f2bfbits(t[(cS + 2) * 33 + lL]) |
                        ((unsigned int)f2bfbits(t[(cS + 3) * 33 + lL]) << 16);
      uint2 u2; u2.x = p0; u2.y = p1;
      *(uint2*)(xT + ((size_t)(b * 1024) + l0 + lL) * 256 + ci0 + cS) = u2;
    }
  } else {
    int t0 = (bid - 2048) * 256 + tid;       // 0..9215
#pragma unroll
    for (int s = 0; s < 8; ++s) {
      int u = s * 9216 + t0;                 // dst uint4 index 0..73727
      int chunkblk = u / 2304;
      int within = u - chunkblk * 2304;
      int co63 = within / 36;
      int r = within - co63 * 36;            // kidx*4 + cig
      int kidx = r >> 2, cig = r & 3;
      int co = (chunkblk >> 3) * 64 + co63;
      int ci = (chunkblk & 7) * 32 + cig * 8;
      union { unsigned short h[8]; uint4 u4; } pk;
#pragma unroll
      for (int j = 0; j < 8; ++j)
        pk.h[j] = f2bfbits(wout[(size_t)(co * 256 + ci + j) * 9 + kidx]);
      *(uint4*)(wo_bf + (size_t)u * 8) = pk.u4;
    }
  }
}

// ---------------------------------------------------------------------------
// K1: 3x3 conv 256->256 via 9 shift-GEMMs, MFMA bf16.
// Block: 64 co x 128 spatial (4 rows). grid 256 = b(8) x cotile(4) x rowchunk(8).
// LDS: wS[64 co][296] (288 = 9 kidx * 32 ci), xS[6 rows][34 cols][40] (32 ci used).
// ---------------------------------------------------------------------------
__global__ __launch_bounds__(256) void conv3_mfma_kernel(
    const bf16* __restrict__ xT, const bf16* __restrict__ wo_bf,
    const float* __restrict__ bias, float* __restrict__ out)
{
  __shared__ __align__(16) short smem[27104];
  short* wS = smem;            // 64*296 = 18944
  short* xS = smem + 18944;    // 6*34*40 = 8160

  int tid = threadIdx.x, lane = tid & 63, wave = tid >> 6;
  int m16 = lane & 15, quad = lane >> 4;
  int bid = blockIdx.x;
  int rc = bid & 7, cotile = (bid >> 3) & 3, b = bid >> 5;
  int y0 = rc * 4;

  f32x4 acc[8];
#pragma unroll
  for (int t = 0; t < 8; ++t) acc[t] = (f32x4){0.f, 0.f, 0.f, 0.f};

  for (int ck = 0; ck < 8; ++ck) {
    __syncthreads();
    const bf16* wbase = wo_bf + (size_t)(cotile * 8 + ck) * 18432;
#pragma unroll
    for (int r = 0; r < 9; ++r) {            // 2304 uint4 units
      int u = r * 256 + tid;
      *(uint4*)(wS + (u / 36) * 296 + (u % 36) * 8) = *(const uint4*)(wbase + (size_t)u * 8);
    }
#pragma unroll
    for (int r = 0; r < 3; ++r) {            // 768 units: 6 rows x 32 cols x 4 segs
      int u = r * 256 + tid;
      int pos = u >> 2, seg = u & 3;
      int row = pos >> 5, col = pos & 31;
      int gy = y0 - 1 + row;
      uint4 val = make_uint4(0u, 0u, 0u, 0u);
      if (gy >= 0 && gy < 32)
        val = *(const uint4*)(xT + ((size_t)(b * 1024) + gy * 32 + col) * 256 + ck * 32 + seg * 8);
      *(uint4*)(xS + (row * 34 + col + 1) * 40 + seg * 8) = val;
    }
    if (tid < 48) {                           // zero halo cols (x=-1 and x=32)
      int pos = tid >> 2, seg = tid & 3;
      int row = pos >> 1, side = pos & 1;
      *(uint4*)(xS + (row * 34 + side * 33) * 40 + seg * 8) = make_uint4(0u, 0u, 0u, 0u);
    }
    __syncthreads();
#pragma unroll
    for (int kidx = 0; kidx < 9; ++kidx) {
      int dy = kidx / 3, dx = kidx - dy * 3;
      bf16x8 af = *(const bf16x8*)(wS + (wave * 16 + m16) * 296 + kidx * 32 + quad * 8);
#pragma unroll
      for (int t = 0; t < 8; ++t) {
        int row = (t >> 1) + dy;
        int col = (t & 1) * 16 + m16 + dx;
        bf16x8 bf = *(const bf16x8*)(xS + (row * 34 + col) * 40 + quad * 8);
        acc[t] = __builtin_amdgcn_mfma_f32_16x16x32_bf16(af, bf, acc[t], 0, 0, 0);
      }
    }
  }

  int cob = cotile * 64 + wave * 16 + quad * 4;
#pragma unroll
  for (int i = 0; i < 4; ++i) {
    float bv = bias[cob + i];
#pragma unroll
    for (int t = 0; t < 8; ++t) {
      int y = y0 + (t >> 1), xc = (t & 1) * 16 + m16;
      out[((size_t)(b * 512) + cob + i) * 1024 + y * 32 + xc] = acc[t][i] + bv;
    }
  }
}

// ---------------------------------------------------------------------------
// K2: qkv 1x1 conv as MFMA GEMM 768 x 1024 x 256 per batch.
// Block: 64 c x 128 l. grid (8 ltile, 12 ctile, 8 b).
// Epilogue: per-wave LDS transpose -> coalesced stores (q/k row-major, v d-major).
// ---------------------------------------------------------------------------
__global__ __launch_bounds__(256) void qkv_mfma_kernel(
    const bf16* __restrict__ xT, const float* __restrict__ wq, const float* __restrict__ bias,
    bf16* __restrict__ qT, bf16* __restrict__ kR, bf16* __restrict__ vW)
{
  __shared__ __align__(16) short smem[13824];
  short* aS = smem;            // [64][72]
  short* bS = smem + 4608;     // [128][72]

  int tid = threadIdx.x, lane = tid & 63, wave = tid >> 6;
  int m16 = lane & 15, quad = lane >> 4;
  int l0 = blockIdx.x * 128;
  int ctile = blockIdx.y;
  int b = blockIdx.z;
  int cbase = ctile * 64;

  f32x4 acc[8];
#pragma unroll
  for (int t = 0; t < 8; ++t) acc[t] = (f32x4){0.f, 0.f, 0.f, 0.f};

  for (int ck = 0; ck < 4; ++ck) {
    __syncthreads();
#pragma unroll
    for (int r = 0; r < 4; ++r) {            // A: 64 c x 64 ci from f32, cvt
      int u = r * 256 + tid;                  // 1024 float4 units
      int c = u >> 4, s4 = u & 15;
      float4 v = *(const float4*)(wq + (size_t)(cbase + c) * 256 + ck * 64 + s4 * 4);
      unsigned int p0 = (unsigned int)f2bfbits(v.x) | ((unsigned int)f2bfbits(v.y) << 16);
      unsigned int p1 = (unsigned int)f2bfbits(v.z) | ((unsigned int)f2bfbits(v.w) << 16);
      uint2 u2; u2.x = p0; u2.y = p1;
      *(uint2*)(aS + c * 72 + s4 * 4) = u2;
    }
#pragma unroll
    for (int r = 0; r < 4; ++r) {            // B: 128 l x 64 ci bf16
      int u = r * 256 + tid;                  // 1024 uint4 units
      int l = u >> 3, seg = u & 7;
      *(uint4*)(bS + l * 72 + seg * 8) =
          *(const uint4*)(xT + ((size_t)(b * 1024) + l0 + l) * 256 + ck * 64 + seg * 8);
    }
    __syncthreads();
#pragma unroll
    for (int ks = 0; ks < 2; ++ks) {
      bf16x8 af = *(const bf16x8*)(aS + (wave * 16 + m16) * 72 + ks * 32 + quad * 8);
#pragma unroll
      for (int t = 0; t < 8; ++t) {
        bf16x8 bf = *(const bf16x8*)(bS + (t * 16 + m16) * 72 + ks * 32 + quad * 8);
        acc[t] = __builtin_amdgcn_mfma_f32_16x16x32_bf16(af, bf, acc[t], 0, 0, 0);
      }
    }
  }

  __syncthreads();   // all waves done reading aS/bS; alias as transpose scratch
  short* ldsT = smem + wave * 3072;          // per-wave [128 l][24] (16 c used)
  int cb = cbase + wave * 16;
  bool isq = (ctile < 4);
  float bv[4];
#pragma unroll
  for (int i = 0; i < 4; ++i) bv[i] = bias[cb + quad * 4 + i];
#pragma unroll
  for (int t = 0; t < 8; ++t) {
#pragma unroll
    for (int i = 0; i < 4; ++i) {
      float v = acc[t][i] + bv[i];
      if (isq) v *= 0.17677669529663689f;    // 32^-0.5, pre-rel-logits
      ldsT[(t * 16 + m16) * 24 + quad * 4 + i] = (short)f2bfbits(v);
    }
  }
  // per-wave region, same-wave readback: compiler's lgkmcnt ordering suffices
  if (ctile < 8) {
    bf16* dst = isq ? qT : kR;
    int coff = isq ? cb : cb - 256;
#pragma unroll
    for (int rep = 0; rep < 4; ++rep) {
      int u = rep * 64 + lane;
      int l = u >> 1, half = u & 1;
      int c0 = coff + half * 8;
      int head = b * 8 + (c0 >> 5), d0 = c0 & 31;
      *(uint4*)(dst + ((size_t)head * 1024 + l0 + l) * 32 + d0) =
          *(const uint4*)(ldsT + l * 24 + half * 8);
    }
  } else {
    int dcol = lane >> 2, lg = lane & 3;
    int c2 = (cb - 512) + dcol;
    int head = b * 8 + (c2 >> 5), gd = c2 & 31;
#pragma unroll
    for (int s = 0; s < 4; ++s) {
      union { unsigned int w[4]; uint4 u4; } pk;
#pragma unroll
      for (int p = 0; p < 4; ++p) {
        int j0 = lg * 32 + s * 8 + p * 2;
        unsigned int u0 = (unsigned short)ldsT[j0 * 24 + dcol];
        unsigned int u1 = (unsigned short)ldsT[(j0 + 1) * 24 + dcol];
        pk.w[p] = u0 | (u1 << 16);
      }
      *(uint4*)(vW + ((size_t)head * 32 + gd) * 1024 + l0 + lg * 32 + s * 8) = pk.u4;
    }
  }
}

// ---------------------------------------------------------------------------
// K3: MFMA attention, augmented-K rel logits. Round-6 changes:
//  - register prefetch of next K/V chunk (hides global latency across barriers)
//  - persistent one-hot: RW one-hot (32+key&31) is chunk-invariant; RH one-hot
//    shifts by +2 per chunk (2 scalar LDS stores vs 64 VALU ops/chunk)
//  - cheap bf16 rounding on hot converts
//  - XCD-aware swizzle: all 16 q-tiles of a head on one XCD (L2 reuse)
// ---------------------------------------------------------------------------
__global__ __launch_bounds__(256) void attn_mfma_kernel(
    const bf16* __restrict__ qT, const bf16* __restrict__ kR, const bf16* __restrict__ vW,
    const float* __restrict__ krw, const float* __restrict__ krh,
    bf16* __restrict__ attL)
{
  __shared__ __align__(16) char smem[31232];
  short* kaugS  = (short*)smem;              // [64 key][104]: k(32)|RWoh(32)|RHoh(32)
  short* vtS    = (short*)(smem + 13312);    // [32 d][72]
  short* atileS = (short*)(smem + 17920);    // prologue Atile / loop pS
  float* krwS   = (float*)smem;              // prologue alias
  float* krhS   = krwS + 63 * 33;

  int tid = threadIdx.x;
  int lane = tid & 63, wave = tid >> 6;
  int m16 = lane & 15, quad = lane >> 4;
  int bid = blockIdx.x;
  // same head -> same blockIdx mod 8 -> same XCD (round-robin heuristic)
  int head = ((bid & 7) << 3) | ((bid >> 3) & 7);
  int qt = bid >> 6;
  int row0 = qt * 64;
  int b = head >> 3, h = head & 7;

  // staging roles + chunk-0 prefetch (issue early; prologue hides latency)
  int skey = tid >> 2, sseg = tid & 3;       // K: 64 keys x 4 segs of 8
  int svd = tid >> 3, svk = tid & 7;         // V: 32 d x 8 key-segs of 8
  const bf16* kptr = kR + (size_t)head * 32768 + skey * 32 + sseg * 8;
  const bf16* vptr = vW + (size_t)head * 32768 + svd * 1024 + svk * 8;
  uint4 kreg = *(const uint4*)kptr;
  uint4 vreg = *(const uint4*)vptr;

  // ---- phase 0: stage krw/krh (padded x33) and q rows into Atile ----
  for (int i = tid; i < 504; i += 256) {
    int row = i >> 3, d0 = (i & 7) * 4;
    float4 a = *(const float4*)(krw + row * 32 + d0);
    krwS[row * 33 + d0 + 0] = a.x; krwS[row * 33 + d0 + 1] = a.y;
    krwS[row * 33 + d0 + 2] = a.z; krwS[row * 33 + d0 + 3] = a.w;
    float4 c = *(const float4*)(krh + row * 32 + d0);
    krhS[row * 33 + d0 + 0] = c.x; krhS[row * 33 + d0 + 1] = c.y;
    krhS[row * 33 + d0 + 2] = c.z; krhS[row * 33 + d0 + 3] = c.w;
  }
  {
    int r = tid >> 2, seg = tid & 3;
    uint4 u = *(const uint4*)(qT + ((size_t)head * 1024 + row0 + r) * 32 + seg * 8);
    *(uint4*)(atileS + r * 104 + seg * 8) = u;
  }
  __syncthreads();

  // ---- phase 1: RW/RH tables -> Atile[.][32..96) ----
  {
    int r = tid >> 2, jseg = tid & 3;
    int qi = r & 31;
    int qx = qt * 2 + (r >> 5);
    float q32[32];
#pragma unroll
    for (int s4 = 0; s4 < 4; ++s4) {
      uint4 u = ((const uint4*)(atileS + r * 104))[s4];
      q32[s4 * 8 + 0] = blo(u.x); q32[s4 * 8 + 1] = bhi(u.x);
      q32[s4 * 8 + 2] = blo(u.y); q32[s4 * 8 + 3] = bhi(u.y);
      q32[s4 * 8 + 4] = blo(u.z); q32[s4 * 8 + 5] = bhi(u.z);
      q32[s4 * 8 + 6] = blo(u.w); q32[s4 * 8 + 7] = bhi(u.w);
    }
    unsigned int pw[4], ph[4];
#pragma unroll
    for (int jp = 0; jp < 4; ++jp) {
      float sv[4] = {0.f, 0.f, 0.f, 0.f};
#pragma unroll 2
      for (int half = 0; half < 2; ++half) {
        int j = jseg * 8 + jp * 2 + half;
        const float* kw = krwS + (j - qi + 31) * 33;
        const float* kh = krhS + (j - qx + 31) * 33;
        float s1 = 0.f, s2 = 0.f;
#pragma unroll
        for (int d = 0; d < 32; ++d) { s1 += q32[d] * kw[d]; s2 += q32[d] * kh[d]; }
        sv[half] = s1; sv[2 + half] = s2;
      }
      pw[jp] = (unsigned int)(unsigned short)f2bfr(sv[0]) |
               ((unsigned int)(unsigned short)f2bfr(sv[1]) << 16);
      ph[jp] = (unsigned int)(unsigned short)f2bfr(sv[2]) |
               ((unsigned int)(unsigned short)f2bfr(sv[3]) << 16);
    }
#pragma unroll
    for (int jp = 0; jp < 4; ++jp) {
      ((unsigned int*)(atileS + r * 104 + 32 + jseg * 8))[jp] = pw[jp];
      ((unsigned int*)(atileS + r * 104 + 64 + jseg * 8))[jp] = ph[jp];
    }
  }
  __syncthreads();   // phase1 reads of krwS/krhS done; kaugS region now free

  // ---- one-hot init (once): zero [32,96), set RW one at 32+(key&31) ----
  {
    union { short s[16]; uint4 u4[2]; } oh;
#pragma unroll
    for (int e = 0; e < 16; ++e) oh.s[e] = 0;
    int base = 32 + sseg * 16;
    int pos = 32 + (skey & 31);
    if (pos >= base && pos < base + 16) oh.s[pos - base] = (short)0x3F80;
    ((uint4*)(kaugS + skey * 104 + 32 + sseg * 16))[0] = oh.u4[0];
    *((uint4*)(kaugS + skey * 104 + 32 + sseg * 16) + 1) = oh.u4[1];
  }

  // ---- persistent A-frags (q | RW | RH) ----
  bf16x8 afrag[3];
  {
    int arow = wave * 16 + m16;
#pragma unroll
    for (int ks = 0; ks < 3; ++ks)
      afrag[ks] = *(const bf16x8*)(atileS + arow * 104 + ks * 32 + quad * 8);
  }

  // ---- K-loop over 16 chunks of 64 keys, register-prefetched ----
  f32x4 oacc[2];
  oacc[0] = (f32x4){0.f, 0.f, 0.f, 0.f};
  oacc[1] = (f32x4){0.f, 0.f, 0.f, 0.f};
  float rsp[4] = {0.f, 0.f, 0.f, 0.f};
  short* pS = (short*)(smem + 17920) + wave * 1152;   // [16 q][72 key-padded]

  for (int c = 0; c < 16; ++c) {
    __syncthreads();                          // prev compute done reading LDS
    *(uint4*)(kaugS + skey * 104 + sseg * 8) = kreg;
    if (sseg == 0) {                          // RH one-hot shift (+2 per chunk)
      if (c) kaugS[skey * 104 + 64 + (c - 1) * 2 + (skey >> 5)] = 0;
      kaugS[skey * 104 + 64 + c * 2 + (skey >> 5)] = (short)0x3F80;
    }
    *(uint4*)(vtS + svd * 72 + svk * 8) = vreg;
    if (c < 15) {                             // prefetch next chunk (latency
      kreg = *(const uint4*)(kptr + (c + 1) * 2048);  //  overlaps compute below)
      vreg = *(const uint4*)(vptr + (c + 1) * 64);
    }
    __syncthreads();                          // staging visible

    // QK^T (augmented K-dim 96): 4 n-tiles x 3 k-steps
    f32x4 sacc[4];
#pragma unroll
    for (int t = 0; t < 4; ++t) sacc[t] = (f32x4){0.f, 0.f, 0.f, 0.f};
#pragma unroll
    for (int t = 0; t < 4; ++t) {
#pragma unroll
      for (int ks = 0; ks < 3; ++ks) {
        bf16x8 bfK = *(const bf16x8*)(kaugS + (t * 16 + m16) * 104 + ks * 32 + quad * 8);
        sacc[t] = __builtin_amdgcn_mfma_f32_16x16x32_bf16(afrag[ks], bfK, sacc[t], 0, 0, 0);
      }
    }
    // exp (no max-sub: logits bounded), row-sum partials, P -> LDS (C/D->A)
#pragma unroll
    for (int t = 0; t < 4; ++t) {
#pragma unroll
      for (int i = 0; i < 4; ++i) {
        float e = __expf(sacc[t][i]);
        rsp[i] += e;
        pS[(quad * 4 + i) * 72 + t * 16 + m16] = f2bfr(e);
      }
    }
    // PV: 2 k-steps (32 keys) x 2 d-tiles
#pragma unroll
    for (int ks2 = 0; ks2 < 2; ++ks2) {
      bf16x8 pf = *(const bf16x8*)(pS + m16 * 72 + ks2 * 32 + quad * 8);
#pragma unroll
      for (int dt = 0; dt < 2; ++dt) {
        bf16x8 vf = *(const bf16x8*)(vtS + (dt * 16 + m16) * 72 + ks2 * 32 + quad * 8);
        oacc[dt] = __builtin_amdgcn_mfma_f32_16x16x32_bf16(pf, vf, oacc[dt], 0, 0, 0);
      }
    }
  }

  // ---- epilogue: reduce row-sums within quad, normalize, store ----
#pragma unroll
  for (int off = 1; off < 16; off <<= 1)
#pragma unroll
    for (int i = 0; i < 4; ++i) rsp[i] += __shfl_xor(rsp[i], off, 64);
#pragma unroll
  for (int i = 0; i < 4; ++i) {
    float invs = 1.0f / rsp[i];
    int grow = row0 + wave * 16 + quad * 4 + i;
#pragma unroll
    for (int dt = 0; dt < 2; ++dt) {
      attL[((size_t)b * 1024 + grow) * 256 + h * 32 + dt * 16 + m16] =
          __float2bfloat16(oacc[dt][i] * invs);
    }
  }
}

// ---------------------------------------------------------------------------
// K4: attnout 1x1 conv as MFMA GEMM 256 x 1024 x 256 per batch.
// Block: 64 co x 128 l. grid (8 ltile, 4 cotile, 8 b) = 256 blocks.
// Epilogue: direct fp32 stores, C/D-layout -> 64B-contiguous runs along l.
// ---------------------------------------------------------------------------
__global__ __launch_bounds__(256) void attnout_mfma_kernel(
    const bf16* __restrict__ attL, const float* __restrict__ w, const float* __restrict__ bias,
    float* __restrict__ out)
{
  __shared__ __align__(16) short smem[13824];
  short* aS = smem;            // [64 co][72]
  short* bS = smem + 4608;     // [128 l][72]

  int tid = threadIdx.x, lane = tid & 63, wave = tid >> 6;
  int m16 = lane & 15, quad = lane >> 4;
  int l0 = blockIdx.x * 128;
  int cotile = blockIdx.y;
  int b = blockIdx.z;
  int cbase = cotile * 64;

  f32x4 acc[8];
#pragma unroll
  for (int t = 0; t < 8; ++t) acc[t] = (f32x4){0.f, 0.f, 0.f, 0.f};

  for (int ck = 0; ck < 4; ++ck) {
    __syncthreads();
#pragma unroll
    for (int r = 0; r < 4; ++r) {            // A: 64 co x 64 ci from f32, cvt
      int u = r * 256 + tid;                  // 1024 float4 units
      int c = u >> 4, s4 = u & 15;
      float4 v = *(const float4*)(w + (size_t)(cbase + c) * 256 + ck * 64 + s4 * 4);
      unsigned int p0 = (unsigned int)f2bfbits(v.x) | ((unsigned int)f2bfbits(v.y) << 16);
      unsigned int p1 = (unsigned int)f2bfbits(v.z) | ((unsigned int)f2bfbits(v.w) << 16);
      uint2 u2; u2.x = p0; u2.y = p1;
      *(uint2*)(aS + c * 72 + s4 * 4) = u2;
    }
#pragma unroll
    for (int r = 0; r < 4; ++r) {            // B: 128 l x 64 ci bf16
      int u = r * 256 + tid;                  // 1024 uint4 units
      int l = u >> 3, seg = u & 7;
      *(uint4*)(bS + l * 72 + seg * 8) =
          *(const uint4*)(attL + ((size_t)(b * 1024) + l0 + l) * 256 + ck * 64 + seg * 8);
    }
    __syncthreads();
#pragma unroll
    for (int ks = 0; ks < 2; ++ks) {
      bf16x8 af = *(const bf16x8*)(aS + (wave * 16 + m16) * 72 + ks * 32 + quad * 8);
#pragma unroll
      for (int t = 0; t < 8; ++t) {
        bf16x8 bf = *(const bf16x8*)(bS + (t * 16 + m16) * 72 + ks * 32 + quad * 8);
        acc[t] = __builtin_amdgcn_mfma_f32_16x16x32_bf16(af, bf, acc[t], 0, 0, 0);
      }
    }
  }

  int co = cbase + wave * 16 + quad * 4;
#pragma unroll
  for (int i = 0; i < 4; ++i) {
    float bv = bias[co + i];
    size_t obase = ((size_t)(b * 512) + 256 + co + i) * 1024 + l0;
#pragma unroll
    for (int t = 0; t < 8; ++t)
      out[obase + t * 16 + m16] = acc[t][i] + bv;
  }
}

// ---------------------------------------------------------------------------
extern "C" void kernel_launch(void* const* d_in, const int* in_sizes, int n_in,
                              void* d_out, int out_size, void* d_ws, size_t ws_size,
                              hipStream_t stream) {
  const float* x      = (const float*)d_in[0];
  const float* w_qkv  = (const float*)d_in[1];
  const float* b_qkv  = (const float*)d_in[2];
  const float* w_attn = (const float*)d_in[3];
  const float* b_attn = (const float*)d_in[4];
  const float* w_out  = (const float*)d_in[5];
  const float* b_out  = (const float*)d_in[6];
  const float* krw    = (const float*)d_in[7];
  const float* krh    = (const float*)d_in[8];
  float* out = (float*)d_out;

  bf16* ws    = (bf16*)d_ws;
  bf16* xT    = ws;                 // [0, 2,097,152)   dead after qkv
  bf16* attL  = ws;                 // alias of xT      (attn -> attnout)
  bf16* wo_bf = ws + 2097152;       // [2,097,152, 2,686,976)  dead after conv3
  bf16* qT    = ws + 2097152;       // [2,097,152, 4,194,304)  written after conv3
  bf16* kR    = ws + 4194304;       // [4,194,304, 6,291,456)
  bf16* vW    = ws + 6291456;       // [6,291,456, 8,388,608)  exact 16 MB fit

  prep_kernel<<<dim3(2084), 256, 0, stream>>>(x, w_out, xT, wo_bf);
  conv3_mfma_kernel<<<dim3(256), 256, 0, stream>>>(xT, wo_bf, b_out, out);
  qkv_mfma_kernel<<<dim3(8, 12, 8), 256, 0, stream>>>(xT, w_qkv, b_qkv, qT, kR, vW);
  attn_mfma_kernel<<<dim3(1024), 256, 0, stream>>>(qT, kR, vW, krw, krh, attL);
  attnout_mfma_kernel<<<dim3(8, 4, 8), 256, 0, stream>>>(attL, w_attn, b_attn, out);
}